// Round 9
// baseline (1109.096 us; speedup 1.0000x reference)
//
#include <hip/hip_runtime.h>

typedef unsigned short u16;
typedef unsigned int   u32;
typedef short short8 __attribute__((ext_vector_type(8)));
typedef float f32x4  __attribute__((ext_vector_type(4)));

#define DEV static __device__ __forceinline__

static constexpr int S_ = 1024;   // seq len
static constexpr int D_ = 256;    // model dim
static constexpr int NR = 4096;   // B*S rows

DEV u16 f2bf(float x) {
    u32 u = __float_as_uint(x);
    return (u16)((u + 0x7FFFu + ((u >> 16) & 1u)) >> 16);
}
DEV float bf2f(u16 s) { return __uint_as_float(((u32)s) << 16); }

// ---------------- elementwise / prep kernels ----------------

__global__ __launch_bounds__(256) void k_fillf(float* __restrict__ o, int n, float v) {
    int i = blockIdx.x * 256 + threadIdx.x;
    if (i < n) o[i] = v;
}

// all-weights f32->bf16 conversion in ONE dispatch; dst contiguous in alloc order.
__global__ __launch_bounds__(256) void k_conv_all(
        const float* __restrict__ s0, const float* __restrict__ s1, const float* __restrict__ s2,
        const float* __restrict__ s3, const float* __restrict__ s4, const float* __restrict__ s5,
        const float* __restrict__ s6, const float* __restrict__ s7, const float* __restrict__ s8,
        const float* __restrict__ s9, u16* __restrict__ dst) {
    constexpr int c0 = 786432/4,            c1 = c0 + 262144/4,  c2 = c1 + 2097152/4,
                  c3 = c2 + 2097152/4,      c4 = c3 + 786432/4,  c5 = c4 + 262144/4,
                  c6 = c5 + 786432/4,       c7 = c6 + 262144/4,  c8 = c7 + 2097152/4,
                  c9 = c8 + 2097152/4;
    for (int i = blockIdx.x * 256 + threadIdx.x; i < c9; i += gridDim.x * 256) {
        const float* src; int base;
        if      (i < c0) { src = s0; base = 0;  }
        else if (i < c1) { src = s1; base = c0; }
        else if (i < c2) { src = s2; base = c1; }
        else if (i < c3) { src = s3; base = c2; }
        else if (i < c4) { src = s4; base = c3; }
        else if (i < c5) { src = s5; base = c4; }
        else if (i < c6) { src = s6; base = c5; }
        else if (i < c7) { src = s7; base = c6; }
        else if (i < c8) { src = s8; base = c7; }
        else             { src = s9; base = c8; }
        float4 v = ((const float4*)src)[i - base];
        ushort4 o; o.x = f2bf(v.x); o.y = f2bf(v.y); o.z = f2bf(v.z); o.w = f2bf(v.w);
        ((ushort4*)dst)[i] = o;
    }
}

__global__ __launch_bounds__(256) void k_embed(const int* __restrict__ xx,
                                               const float* __restrict__ cb,
                                               const float* __restrict__ pos,
                                               float* __restrict__ hf, u16* __restrict__ hb) {
    int wid = threadIdx.x >> 6, lane = threadIdx.x & 63;
    int row = blockIdx.x * 4 + wid;         // 0..4095
    int sp = row & (S_ - 1);
    int tok = xx[row];
    float4 c = ((const float4*)(cb + (size_t)tok * D_))[lane];
    float4 p = ((const float4*)(pos + (size_t)sp * D_))[lane];
    float4 s; s.x = c.x + p.x; s.y = c.y + p.y; s.z = c.z + p.z; s.w = c.w + p.w;
    ((float4*)(hf + (size_t)row * D_))[lane] = s;
    ushort4 o; o.x = f2bf(s.x); o.y = f2bf(s.y); o.z = f2bf(s.z); o.w = f2bf(s.w);
    ((ushort4*)(hb + (size_t)row * D_))[lane] = o;
}

__global__ __launch_bounds__(256) void k_addv(const unsigned char* __restrict__ mask,
                                              float* __restrict__ av, float* __restrict__ avz) {
    int i = blockIdx.x * 256 + threadIdx.x;
    if (i < NR) { av[i] = mask[i] ? -2.0e9f : 0.0f; avz[i] = 0.0f; }
}

// residual + layernorm; writes f32 master and bf16 copy
__global__ __launch_bounds__(256) void k_ln(const float* __restrict__ x, const float* __restrict__ y,
                                            const float* __restrict__ gg, const float* __restrict__ bb,
                                            float* __restrict__ of, u16* __restrict__ ob) {
    int wid = threadIdx.x >> 6, lane = threadIdx.x & 63;
    int row = blockIdx.x * 4 + wid;
    float4 xv = ((const float4*)(x + (size_t)row * D_))[lane];
    float4 yv = ((const float4*)(y + (size_t)row * D_))[lane];
    float4 s; s.x = xv.x + yv.x; s.y = xv.y + yv.y; s.z = xv.z + yv.z; s.w = xv.w + yv.w;
    float sum = s.x + s.y + s.z + s.w;
    float sq  = s.x * s.x + s.y * s.y + s.z * s.z + s.w * s.w;
    #pragma unroll
    for (int m = 1; m < 64; m <<= 1) { sum += __shfl_xor(sum, m, 64); sq += __shfl_xor(sq, m, 64); }
    float mean = sum * (1.0f / 256.0f);
    float var  = sq * (1.0f / 256.0f) - mean * mean;
    float rs = rsqrtf(var + 1e-5f);
    float4 gv = ((const float4*)gg)[lane];
    float4 bv = ((const float4*)bb)[lane];
    float4 o;
    o.x = (s.x - mean) * rs * gv.x + bv.x;
    o.y = (s.y - mean) * rs * gv.y + bv.y;
    o.z = (s.z - mean) * rs * gv.z + bv.z;
    o.w = (s.w - mean) * rs * gv.w + bv.w;
    ((float4*)(of + (size_t)row * D_))[lane] = o;
    ushort4 ub; ub.x = f2bf(o.x); ub.y = f2bf(o.y); ub.z = f2bf(o.z); ub.w = f2bf(o.w);
    ((ushort4*)(ob + (size_t)row * D_))[lane] = ub;
}

// ---------------- direct-to-register MFMA GEMM: C = A @ W^T + bias ----------------
// No LDS, no barriers: each lane loads its 16x16x32 fragment (one uint4) straight from
// global. Compiler emits counted vmcnt within the wave; unroll-4 keeps loads in flight.
// Wave-autonomous 16FM x 16FN output tile; 4 waves/block; XCD-chunked wave id.

template <int FM, int FN, bool RELU, bool OBF16>
__global__ __launch_bounds__(256) void k_gemm_reg(const u16* __restrict__ A, const u16* __restrict__ Bw,
                                                  const float* __restrict__ bias,
                                                  float* __restrict__ Cf, u16* __restrict__ Cb,
                                                  int Nn, int Kk) {
    int tid = threadIdx.x, w = tid >> 6, lane = tid & 63;
    int lr = lane & 15, g = lane >> 4;
    int bid = blockIdx.x, nwg = gridDim.x;
    if ((nwg & 7) == 0) bid = (bid & 7) * (nwg >> 3) + (bid >> 3);   // XCD-chunked (bijective)
    int gwid = bid * 4 + w;
    int ntile = Nn / (16 * FN);
    int m0 = (gwid / ntile) * 16 * FM, n0 = (gwid % ntile) * 16 * FN;

    const u16* ab[FM];
    const u16* bb[FN];
    #pragma unroll
    for (int mi = 0; mi < FM; mi++) ab[mi] = A  + (size_t)(m0 + mi * 16 + lr) * Kk + g * 8;
    #pragma unroll
    for (int ni = 0; ni < FN; ni++) bb[ni] = Bw + (size_t)(n0 + ni * 16 + lr) * Kk + g * 8;

    f32x4 acc[FM][FN] = {};
    #pragma unroll 4
    for (int kb = 0; kb < Kk; kb += 32) {
        short8 af[FM], bf[FN];
        #pragma unroll
        for (int mi = 0; mi < FM; mi++) af[mi] = *(const short8*)(ab[mi] + kb);
        #pragma unroll
        for (int ni = 0; ni < FN; ni++) bf[ni] = *(const short8*)(bb[ni] + kb);
        #pragma unroll
        for (int mi = 0; mi < FM; mi++)
            #pragma unroll
            for (int ni = 0; ni < FN; ni++)
                acc[mi][ni] = __builtin_amdgcn_mfma_f32_16x16x32_bf16(af[mi], bf[ni], acc[mi][ni], 0, 0, 0);
    }

    #pragma unroll
    for (int ni = 0; ni < FN; ni++) {
        int col = n0 + ni * 16 + lr;
        float bi = bias[col];
        #pragma unroll
        for (int mi = 0; mi < FM; mi++) {
            #pragma unroll
            for (int jj = 0; jj < 4; jj++) {
                int row = m0 + mi * 16 + g * 4 + jj;
                float v = acc[mi][ni][jj] + bi;
                if (RELU) v = fmaxf(v, 0.0f);
                if (OBF16) Cb[(size_t)row * Nn + col] = f2bf(v);
                else       Cf[(size_t)row * Nn + col] = v;
            }
        }
    }
}

// ---------------- MFMA flash attention (HD=32), bf16 in, bf16 out ----------------
// grid = 512, XCD-chunked (each XCD owns 4 whole heads -> K/V L2-resident).
// 4 waves, 16 q-rows each. swapped QK^T; padded-linear LDS; natural-domain softmax.

__global__ __launch_bounds__(256) void k_attn(const u16* __restrict__ qp, int qs,
                                              const u16* __restrict__ kvp, int ks, int koff, int voff,
                                              const float* __restrict__ addv, u16* __restrict__ out) {
    __shared__ __align__(16) u16 Kl[128 * 32];       // [key][d] linear
    __shared__ __align__(16) u16 VTl[32 * 136];      // [d][key] padded linear
    __shared__ __align__(16) u16 Pl[4 * 16 * 136];   // per-wave [q][key] padded linear
    __shared__ float Al[128];

    int tid = threadIdx.x, w = tid >> 6, lane = tid & 63;
    int lr = lane & 15, g = lane >> 4;
    int blk = blockIdx.x;
    blk = (blk & 7) * 64 + (blk >> 3);               // XCD-chunked (512 = 8 x 64)
    int qb = blk & 15, h = (blk >> 4) & 7, b = blk >> 7;
    int q0 = qb * 64 + w * 16;
    const float QS = 0.17677669529663687f;   // 1/sqrt(32)

    short8 qf = *(const short8*)(qp + (size_t)(b * S_ + q0 + lr) * qs + h * 32 + g * 8);

    f32x4 o0 = {0.f, 0.f, 0.f, 0.f}, o1 = {0.f, 0.f, 0.f, 0.f};
    float m_run = -3.0e38f, l_run = 0.0f;
    float sreg[8][4];
    u16* Pw = Pl + w * 16 * 136;

    int key_t = tid >> 1, dh = (tid & 1) * 16;    // staging roles
    const u16* kbase = kvp + (size_t)(b * S_) * ks;

    for (int kb = 0; kb < 8; kb++) {
        {
            const u16* srck = kbase + (size_t)(kb * 128 + key_t) * ks + koff + h * 32 + dh;
            uint4 a0 = *(const uint4*)srck;
            uint4 a1 = *(const uint4*)(srck + 8);
            *(uint4*)(Kl + key_t * 32 + dh) = a0;
            *(uint4*)(Kl + key_t * 32 + dh + 8) = a1;
            const u16* srcv = kbase + (size_t)(kb * 128 + key_t) * ks + voff + h * 32 + dh;
            union { uint4 v[2]; u16 s[16]; } vu;
            vu.v[0] = *(const uint4*)srcv; vu.v[1] = *(const uint4*)(srcv + 8);
            #pragma unroll
            for (int i = 0; i < 16; i++) VTl[(dh + i) * 136 + key_t] = vu.s[i];
            if (tid < 128) Al[tid] = addv[b * S_ + kb * 128 + tid];
        }
        __syncthreads();

        #pragma unroll
        for (int t = 0; t < 8; t++) {
            short8 kf = *(const short8*)(Kl + (t * 16 + lr) * 32 + g * 8);
            f32x4 z = {0.f, 0.f, 0.f, 0.f};
            f32x4 st = __builtin_amdgcn_mfma_f32_16x16x32_bf16(kf, qf, z, 0, 0, 0);
            #pragma unroll
            for (int jj = 0; jj < 4; jj++) sreg[t][jj] = st[jj] * QS + Al[t * 16 + g * 4 + jj];
        }

        float mb = -3.0e38f;
        #pragma unroll
        for (int t = 0; t < 8; t++)
            #pragma unroll
            for (int jj = 0; jj < 4; jj++) mb = fmaxf(mb, sreg[t][jj]);
        mb = fmaxf(mb, __shfl_xor(mb, 16, 64));
        mb = fmaxf(mb, __shfl_xor(mb, 32, 64));
        float mnew = fmaxf(m_run, mb);
        float sc = __expf(m_run - mnew);
        float ls = 0.f;
        #pragma unroll
        for (int t = 0; t < 8; t++)
            #pragma unroll
            for (int jj = 0; jj < 4; jj++) {
                float p = __expf(sreg[t][jj] - mnew);
                sreg[t][jj] = p; ls += p;
            }
        ls += __shfl_xor(ls, 16, 64); ls += __shfl_xor(ls, 32, 64);
        l_run = l_run * sc + ls; m_run = mnew;
        #pragma unroll
        for (int jj = 0; jj < 4; jj++) {
            float scj = __shfl(sc, 20 * g + jj, 64);   // lane 16g + (4g+jj): lr' == 4g+jj
            o0[jj] *= scj; o1[jj] *= scj;
        }

        #pragma unroll
        for (int t = 0; t < 8; t++) {
            u32 u0 = (u32)f2bf(sreg[t][0]) | ((u32)f2bf(sreg[t][1]) << 16);
            u32 u1 = (u32)f2bf(sreg[t][2]) | ((u32)f2bf(sreg[t][3]) << 16);
            *(uint2*)(Pw + lr * 136 + t * 16 + g * 4) = make_uint2(u0, u1);
        }

        #pragma unroll
        for (int c = 0; c < 4; c++) {
            short8 pa = *(const short8*)(Pw + lr * 136 + c * 32 + g * 8);
            short8 v0 = *(const short8*)(VTl + lr * 136 + c * 32 + g * 8);
            short8 v1 = *(const short8*)(VTl + (16 + lr) * 136 + c * 32 + g * 8);
            o0 = __builtin_amdgcn_mfma_f32_16x16x32_bf16(pa, v0, o0, 0, 0, 0);
            o1 = __builtin_amdgcn_mfma_f32_16x16x32_bf16(pa, v1, o1, 0, 0, 0);
        }
        __syncthreads();
    }

    float li = 1.0f / l_run;
    #pragma unroll
    for (int jj = 0; jj < 4; jj++) {
        float lij = __shfl(li, 20 * g + jj, 64);
        int r = q0 + g * 4 + jj;
        u16* op = out + (size_t)(b * S_ + r) * 256 + h * 32;
        op[lr]      = f2bf(o0[jj] * lij);
        op[16 + lr] = f2bf(o1[jj] * lij);
    }
}

// ---------------- host orchestration ----------------

extern "C" void kernel_launch(void* const* d_in, const int* in_sizes, int n_in,
                              void* d_out, int out_size, void* d_ws, size_t ws_size,
                              hipStream_t stream) {
    const int* x                = (const int*)d_in[0];
    const unsigned char* mask   = (const unsigned char*)d_in[1];
    const float* codebook       = (const float*)d_in[2];
    const float* pos            = (const float*)d_in[3];
    const float* enc_qkv_w = (const float*)d_in[4];  const float* enc_qkv_b = (const float*)d_in[5];
    const float* enc_out_w = (const float*)d_in[6];  const float* enc_out_b = (const float*)d_in[7];
    const float* enc_ff1_w = (const float*)d_in[8];  const float* enc_ff1_b = (const float*)d_in[9];
    const float* enc_ff2_w = (const float*)d_in[10]; const float* enc_ff2_b = (const float*)d_in[11];
    const float* enc_ln1_g = (const float*)d_in[12]; const float* enc_ln1_b = (const float*)d_in[13];
    const float* enc_ln2_g = (const float*)d_in[14]; const float* enc_ln2_b = (const float*)d_in[15];
    const float* dec_sa_qkv_w = (const float*)d_in[16]; const float* dec_sa_qkv_b = (const float*)d_in[17];
    const float* dec_sa_out_w = (const float*)d_in[18]; const float* dec_sa_out_b = (const float*)d_in[19];
    const float* dec_ca_qkv_w = (const float*)d_in[20]; const float* dec_ca_qkv_b = (const float*)d_in[21];
    const float* dec_ca_out_w = (const float*)d_in[22]; const float* dec_ca_out_b = (const float*)d_in[23];
    const float* dec_ff1_w = (const float*)d_in[24]; const float* dec_ff1_b = (const float*)d_in[25];
    const float* dec_ff2_w = (const float*)d_in[26]; const float* dec_ff2_b = (const float*)d_in[27];
    const float* dec_ln1_g = (const float*)d_in[28]; const float* dec_ln1_b = (const float*)d_in[29];
    const float* dec_ln2_g = (const float*)d_in[30]; const float* dec_ln2_b = (const float*)d_in[31];
    const float* dec_ln3_g = (const float*)d_in[32]; const float* dec_ln3_b = (const float*)d_in[33];

    char* ws = (char*)d_ws; size_t off = 0;
    auto alloc = [&](size_t b) { char* p = ws + off; off += (b + 255) & ~(size_t)255; return p; };

    // bf16 weights — CONTIGUOUS block in k_conv_all segment order
    u16* w_eqkv  = (u16*)alloc((size_t)786432 * 2);
    u16* w_eout  = (u16*)alloc((size_t)262144 * 2);
    u16* w_eff1  = (u16*)alloc((size_t)2097152 * 2);
    u16* w_eff2  = (u16*)alloc((size_t)2097152 * 2);
    u16* w_dsaq  = (u16*)alloc((size_t)786432 * 2);
    u16* w_dsao  = (u16*)alloc((size_t)262144 * 2);
    u16* w_dcaq  = (u16*)alloc((size_t)786432 * 2);
    u16* w_dcao  = (u16*)alloc((size_t)262144 * 2);
    u16* w_dff1  = (u16*)alloc((size_t)2097152 * 2);
    u16* w_dff2  = (u16*)alloc((size_t)2097152 * 2);
    // persistent activations
    float* h_f   = (float*)alloc((size_t)NR * D_ * 4);
    u16*   h_b   = (u16*)  alloc((size_t)NR * D_ * 2);
    float* ctx_f = (float*)alloc((size_t)NR * D_ * 4);
    u16*   ctx_b = (u16*)  alloc((size_t)NR * D_ * 2);
    float* dd_f  = (float*)alloc((size_t)NR * D_ * 4);
    u16*   dd_b  = (u16*)  alloc((size_t)NR * D_ * 2);
    float* gem_f = (float*)alloc((size_t)NR * 256 * 4);
    u16*   attno = (u16*)  alloc((size_t)NR * 256 * 2);
    float* addv  = (float*)alloc((size_t)NR * 4);
    float* addvz = (float*)alloc((size_t)NR * 4);
    // 16MB scratch, time-shared: enc {qkv_b | ffh_b}; dec {v_b -> qca,kvca | ffh_b}
    u16* scr = (u16*)alloc((size_t)NR * 2048 * 2);
    u16* qkv_b = scr;                      // [4096][768] (enc, dead before ffh use)
    u16* ffh_b = scr;                      // [4096][2048]
    u16* v_b   = scr;                      // [4096][256] (dec, dead before qca)
    u16* qca_b = scr;                      // [4096][256]
    u16* kvca_b = scr + (size_t)NR * 256;  // [4096][512]
    (void)in_sizes; (void)n_in;

    // tripwire: if workspace too small, emit sentinel 1000.0 -> absmax ~1000
    if (off > ws_size) {
        k_fillf<<<(out_size + 255) / 256, 256, 0, stream>>>((float*)d_out, out_size, 1000.0f);
        return;
    }

    k_conv_all<<<2048, 256, 0, stream>>>(enc_qkv_w, enc_out_w, enc_ff1_w, enc_ff2_w,
                                         dec_sa_qkv_w, dec_sa_out_w, dec_ca_qkv_w, dec_ca_out_w,
                                         dec_ff1_w, dec_ff2_w, w_eqkv);
    k_addv<<<16, 256, 0, stream>>>(mask, addv, addvz);
    k_embed<<<1024, 256, 0, stream>>>(x, codebook, pos, h_f, h_b);

    // ---- encoder ----
    for (int l = 0; l < 4; l++) {
        const u16* inb = l ? ctx_b : h_b;
        const float* inf = l ? ctx_f : h_f;
        // qkv: M=4096, N=768, K=256 — wave 32x64 -> 1536 waves -> 384 blocks
        k_gemm_reg<2,4,false,true><<<384, 256, 0, stream>>>(inb, w_eqkv + (size_t)l*196608,
            enc_qkv_b + l*768, nullptr, qkv_b, 768, 256);
        k_attn<<<512, 256, 0, stream>>>(qkv_b, 768, qkv_b, 768, 256, 512, addv, attno);
        // out-proj: N=256, K=256 — wave 16x32 -> 2048 waves -> 512 blocks
        k_gemm_reg<1,2,false,false><<<512, 256, 0, stream>>>(attno, w_eout + (size_t)l*65536,
            enc_out_b + l*256, gem_f, nullptr, 256, 256);
        k_ln<<<1024, 256, 0, stream>>>(inf, gem_f, enc_ln1_g + l*256, enc_ln1_b + l*256, ctx_f, ctx_b);
        // ff1: N=2048, K=256 — wave 32x64 -> 4096 waves -> 1024 blocks
        k_gemm_reg<2,4,true,true><<<1024, 256, 0, stream>>>(ctx_b, w_eff1 + (size_t)l*524288,
            enc_ff1_b + l*2048, nullptr, ffh_b, 2048, 256);
        // ff2: N=256, K=2048 — wave 16x32 -> 2048 waves -> 512 blocks
        k_gemm_reg<1,2,false,false><<<512, 256, 0, stream>>>(ffh_b, w_eff2 + (size_t)l*524288,
            enc_ff2_b + l*256, gem_f, nullptr, 256, 2048);
        k_ln<<<1024, 256, 0, stream>>>(ctx_f, gem_f, enc_ln2_g + l*256, enc_ln2_b + l*256, ctx_f, ctx_b);
    }

    // ---- decoder ----
    for (int l = 0; l < 4; l++) {
        const u16* inb = l ? dd_b : h_b;
        const float* inf = l ? dd_f : h_f;
        // self-attn degenerates to out_proj(v_proj(x))
        k_gemm_reg<1,2,false,true><<<512, 256, 0, stream>>>(inb, w_dsaq + (size_t)l*196608 + 131072,
            dec_sa_qkv_b + l*768 + 512, nullptr, v_b, 256, 256);
        k_gemm_reg<1,2,false,false><<<512, 256, 0, stream>>>(v_b, w_dsao + (size_t)l*65536,
            dec_sa_out_b + l*256, gem_f, nullptr, 256, 256);
        k_ln<<<1024, 256, 0, stream>>>(inf, gem_f, dec_ln1_g + l*256, dec_ln1_b + l*256, dd_f, dd_b);
        // cross-attn (v_b dead now; qca/kvca reuse scratch)
        k_gemm_reg<1,2,false,true><<<512, 256, 0, stream>>>(dd_b, w_dcaq + (size_t)l*196608,
            dec_ca_qkv_b + l*768, nullptr, qca_b, 256, 256);
        // kvca: N=512, K=256 — wave 32x32 -> 2048 waves -> 512 blocks
        k_gemm_reg<2,2,false,true><<<512, 256, 0, stream>>>(ctx_b, w_dcaq + (size_t)l*196608 + 65536,
            dec_ca_qkv_b + l*768 + 256, nullptr, kvca_b, 512, 256);
        k_attn<<<512, 256, 0, stream>>>(qca_b, 256, kvca_b, 512, 0, 256, addvz, attno);
        k_gemm_reg<1,2,false,false><<<512, 256, 0, stream>>>(attno, w_dcao + (size_t)l*65536,
            dec_ca_out_b + l*256, gem_f, nullptr, 256, 256);
        k_ln<<<1024, 256, 0, stream>>>(dd_f, gem_f, dec_ln2_g + l*256, dec_ln2_b + l*256, dd_f, dd_b);
        // FFN (qca/kvca dead; ffh reuses scratch)
        k_gemm_reg<2,4,true,true><<<1024, 256, 0, stream>>>(dd_b, w_dff1 + (size_t)l*524288,
            dec_ff1_b + l*2048, nullptr, ffh_b, 2048, 256);
        k_gemm_reg<1,2,false,false><<<512, 256, 0, stream>>>(ffh_b, w_dff2 + (size_t)l*524288,
            dec_ff2_b + l*256, gem_f, nullptr, 256, 2048);
        // final layer: f32 master goes straight to d_out (reference output dtype is float32)
        k_ln<<<1024, 256, 0, stream>>>(dd_f, gem_f, dec_ln3_g + l*256, dec_ln3_b + l*256,
                                       (l == 3) ? (float*)d_out : dd_f, dd_b);
    }
}

// Round 10
// 646.323 us; speedup vs baseline: 1.7160x; 1.7160x over previous
//
#include <hip/hip_runtime.h>

typedef unsigned short u16;
typedef unsigned int   u32;
typedef short short8 __attribute__((ext_vector_type(8)));
typedef float f32x4  __attribute__((ext_vector_type(4)));

#define DEV static __device__ __forceinline__

static constexpr int S_ = 1024;   // seq len
static constexpr int D_ = 256;    // model dim
static constexpr int NR = 4096;   // B*S rows

DEV u16 f2bf(float x) {
    u32 u = __float_as_uint(x);
    return (u16)((u + 0x7FFFu + ((u >> 16) & 1u)) >> 16);
}
DEV float bf2f(u16 s) { return __uint_as_float(((u32)s) << 16); }

// ---------------- elementwise / prep kernels ----------------

__global__ __launch_bounds__(256) void k_fillf(float* __restrict__ o, int n, float v) {
    int i = blockIdx.x * 256 + threadIdx.x;
    if (i < n) o[i] = v;
}

// all-weights f32->bf16 conversion in ONE dispatch; dst contiguous in alloc order.
__global__ __launch_bounds__(256) void k_conv_all(
        const float* __restrict__ s0, const float* __restrict__ s1, const float* __restrict__ s2,
        const float* __restrict__ s3, const float* __restrict__ s4, const float* __restrict__ s5,
        const float* __restrict__ s6, const float* __restrict__ s7, const float* __restrict__ s8,
        const float* __restrict__ s9, u16* __restrict__ dst) {
    constexpr int c0 = 786432/4,            c1 = c0 + 262144/4,  c2 = c1 + 2097152/4,
                  c3 = c2 + 2097152/4,      c4 = c3 + 786432/4,  c5 = c4 + 262144/4,
                  c6 = c5 + 786432/4,       c7 = c6 + 262144/4,  c8 = c7 + 2097152/4,
                  c9 = c8 + 2097152/4;
    for (int i = blockIdx.x * 256 + threadIdx.x; i < c9; i += gridDim.x * 256) {
        const float* src; int base;
        if      (i < c0) { src = s0; base = 0;  }
        else if (i < c1) { src = s1; base = c0; }
        else if (i < c2) { src = s2; base = c1; }
        else if (i < c3) { src = s3; base = c2; }
        else if (i < c4) { src = s4; base = c3; }
        else if (i < c5) { src = s5; base = c4; }
        else if (i < c6) { src = s6; base = c5; }
        else if (i < c7) { src = s7; base = c6; }
        else if (i < c8) { src = s8; base = c7; }
        else             { src = s9; base = c8; }
        float4 v = ((const float4*)src)[i - base];
        ushort4 o; o.x = f2bf(v.x); o.y = f2bf(v.y); o.z = f2bf(v.z); o.w = f2bf(v.w);
        ((ushort4*)dst)[i] = o;
    }
}

__global__ __launch_bounds__(256) void k_embed(const int* __restrict__ xx,
                                               const float* __restrict__ cb,
                                               const float* __restrict__ pos,
                                               float* __restrict__ hf, u16* __restrict__ hb) {
    int wid = threadIdx.x >> 6, lane = threadIdx.x & 63;
    int row = blockIdx.x * 4 + wid;         // 0..4095
    int sp = row & (S_ - 1);
    int tok = xx[row];
    float4 c = ((const float4*)(cb + (size_t)tok * D_))[lane];
    float4 p = ((const float4*)(pos + (size_t)sp * D_))[lane];
    float4 s; s.x = c.x + p.x; s.y = c.y + p.y; s.z = c.z + p.z; s.w = c.w + p.w;
    ((float4*)(hf + (size_t)row * D_))[lane] = s;
    ushort4 o; o.x = f2bf(s.x); o.y = f2bf(s.y); o.z = f2bf(s.z); o.w = f2bf(s.w);
    ((ushort4*)(hb + (size_t)row * D_))[lane] = o;
}

__global__ __launch_bounds__(256) void k_addv(const unsigned char* __restrict__ mask,
                                              float* __restrict__ av, float* __restrict__ avz) {
    int i = blockIdx.x * 256 + threadIdx.x;
    if (i < NR) { av[i] = mask[i] ? -2.0e9f : 0.0f; avz[i] = 0.0f; }
}

// residual + layernorm; writes f32 master and bf16 copy
__global__ __launch_bounds__(256) void k_ln(const float* __restrict__ x, const float* __restrict__ y,
                                            const float* __restrict__ gg, const float* __restrict__ bb,
                                            float* __restrict__ of, u16* __restrict__ ob) {
    int wid = threadIdx.x >> 6, lane = threadIdx.x & 63;
    int row = blockIdx.x * 4 + wid;
    float4 xv = ((const float4*)(x + (size_t)row * D_))[lane];
    float4 yv = ((const float4*)(y + (size_t)row * D_))[lane];
    float4 s; s.x = xv.x + yv.x; s.y = xv.y + yv.y; s.z = xv.z + yv.z; s.w = xv.w + yv.w;
    float sum = s.x + s.y + s.z + s.w;
    float sq  = s.x * s.x + s.y * s.y + s.z * s.z + s.w * s.w;
    #pragma unroll
    for (int m = 1; m < 64; m <<= 1) { sum += __shfl_xor(sum, m, 64); sq += __shfl_xor(sq, m, 64); }
    float mean = sum * (1.0f / 256.0f);
    float var  = sq * (1.0f / 256.0f) - mean * mean;
    float rs = rsqrtf(var + 1e-5f);
    float4 gv = ((const float4*)gg)[lane];
    float4 bv = ((const float4*)bb)[lane];
    float4 o;
    o.x = (s.x - mean) * rs * gv.x + bv.x;
    o.y = (s.y - mean) * rs * gv.y + bv.y;
    o.z = (s.z - mean) * rs * gv.z + bv.z;
    o.w = (s.w - mean) * rs * gv.w + bv.w;
    ((float4*)(of + (size_t)row * D_))[lane] = o;
    ushort4 ub; ub.x = f2bf(o.x); ub.y = f2bf(o.y); ub.z = f2bf(o.z); ub.w = f2bf(o.w);
    ((ushort4*)(ob + (size_t)row * D_))[lane] = ub;
}

// residual + sum-4-partials + layernorm (used after split-K ff2)
__global__ __launch_bounds__(256) void k_ln4(const float* __restrict__ x, const float* __restrict__ yp,
                                             const float* __restrict__ gg, const float* __restrict__ bb,
                                             float* __restrict__ of, u16* __restrict__ ob) {
    int wid = threadIdx.x >> 6, lane = threadIdx.x & 63;
    int row = blockIdx.x * 4 + wid;
    float4 xv = ((const float4*)(x + (size_t)row * D_))[lane];
    float4 s = xv;
    #pragma unroll
    for (int kz = 0; kz < 4; kz++) {
        float4 yv = ((const float4*)(yp + (size_t)kz * NR * D_ + (size_t)row * D_))[lane];
        s.x += yv.x; s.y += yv.y; s.z += yv.z; s.w += yv.w;
    }
    float sum = s.x + s.y + s.z + s.w;
    float sq  = s.x * s.x + s.y * s.y + s.z * s.z + s.w * s.w;
    #pragma unroll
    for (int m = 1; m < 64; m <<= 1) { sum += __shfl_xor(sum, m, 64); sq += __shfl_xor(sq, m, 64); }
    float mean = sum * (1.0f / 256.0f);
    float var  = sq * (1.0f / 256.0f) - mean * mean;
    float rs = rsqrtf(var + 1e-5f);
    float4 gv = ((const float4*)gg)[lane];
    float4 bv = ((const float4*)bb)[lane];
    float4 o;
    o.x = (s.x - mean) * rs * gv.x + bv.x;
    o.y = (s.y - mean) * rs * gv.y + bv.y;
    o.z = (s.z - mean) * rs * gv.z + bv.z;
    o.w = (s.w - mean) * rs * gv.w + bv.w;
    ((float4*)(of + (size_t)row * D_))[lane] = o;
    ushort4 ub; ub.x = f2bf(o.x); ub.y = f2bf(o.y); ub.z = f2bf(o.z); ub.w = f2bf(o.w);
    ((ushort4*)(ob + (size_t)row * D_))[lane] = ub;
}

// ---------------- MFMA GEMM (round-5 structure):  C = A @ W^T + bias ----------------
// Reg-staged uint4 loads -> padded linear LDS (stride 72 u16 = 144B). XCD-chunked bid.

template <int BM, int BN, bool RELU, bool OBF16>
__global__ __launch_bounds__(256) void k_gemm(const u16* __restrict__ A, const u16* __restrict__ Bw,
                                              const float* __restrict__ bias,
                                              float* __restrict__ Cf, u16* __restrict__ Cb,
                                              int Nn, int Kk) {
    constexpr int FM = BM / 32, FN = BN / 32;
    constexpr int LDA = 72;
    __shared__ __align__(16) u16 As[BM * LDA];
    __shared__ __align__(16) u16 Bs[BN * LDA];
    int tid = threadIdx.x, w = tid >> 6, lane = tid & 63;
    int lr = lane & 15, g = lane >> 4;
    int wm = w >> 1, wn = w & 1;
    int nbn = Nn / BN;
    int bid = blockIdx.x, nwg = gridDim.x;
    if ((nwg & 7) == 0) bid = (bid & 7) * (nwg >> 3) + (bid >> 3);   // XCD-chunked (bijective)
    int m0 = (bid / nbn) * BM, n0 = (bid % nbn) * BN;
    int trow = tid >> 3, tcol = (tid & 7) << 3;

    f32x4 acc[FM][FN] = {};

    for (int kb = 0; kb < Kk; kb += 64) {
        if (kb) __syncthreads();
        #pragma unroll
        for (int r = 0; r < BM / 32; r++) {
            int row = r * 32 + trow;
            uint4 v = *(const uint4*)(A + (size_t)(m0 + row) * Kk + kb + tcol);
            *(uint4*)(As + row * LDA + tcol) = v;
        }
        #pragma unroll
        for (int r = 0; r < BN / 32; r++) {
            int row = r * 32 + trow;
            uint4 v = *(const uint4*)(Bw + (size_t)(n0 + row) * Kk + kb + tcol);
            *(uint4*)(Bs + row * LDA + tcol) = v;
        }
        __syncthreads();
        #pragma unroll
        for (int kk = 0; kk < 2; kk++) {
            short8 af[FM], bfr[FN];
            #pragma unroll
            for (int mi = 0; mi < FM; mi++)
                af[mi] = *(const short8*)(As + (wm * (BM / 2) + mi * 16 + lr) * LDA + kk * 32 + g * 8);
            #pragma unroll
            for (int ni = 0; ni < FN; ni++)
                bfr[ni] = *(const short8*)(Bs + (wn * (BN / 2) + ni * 16 + lr) * LDA + kk * 32 + g * 8);
            #pragma unroll
            for (int mi = 0; mi < FM; mi++)
                #pragma unroll
                for (int ni = 0; ni < FN; ni++)
                    acc[mi][ni] = __builtin_amdgcn_mfma_f32_16x16x32_bf16(af[mi], bfr[ni], acc[mi][ni], 0, 0, 0);
        }
    }

    #pragma unroll
    for (int ni = 0; ni < FN; ni++) {
        int col = n0 + wn * (BN / 2) + ni * 16 + lr;
        float bi = bias[col];
        #pragma unroll
        for (int mi = 0; mi < FM; mi++) {
            #pragma unroll
            for (int jj = 0; jj < 4; jj++) {
                int row = m0 + wm * (BM / 2) + mi * 16 + g * 4 + jj;
                float v = acc[mi][ni][jj] + bi;
                if (RELU) v = fmaxf(v, 0.0f);
                if (OBF16) Cb[(size_t)row * Nn + col] = f2bf(v);
                else       Cf[(size_t)row * Nn + col] = v;
            }
        }
    }
}

// ff2 split-K=4 (M=4096, N=256, K=2048): 64^2 tile, grid 1024 = 256 mn-tiles x 4 kz.
// Writes f32 partials Cp[kz][row][col] (no atomics); bias folded into kz==0.
__global__ __launch_bounds__(256) void k_gemm_sk4(const u16* __restrict__ A, const u16* __restrict__ Bw,
                                                  const float* __restrict__ bias, float* __restrict__ Cp) {
    constexpr int LDA = 72, Nn = 256, Kk = 2048;
    __shared__ __align__(16) u16 As[64 * LDA];
    __shared__ __align__(16) u16 Bs[64 * LDA];
    int tid = threadIdx.x, w = tid >> 6, lane = tid & 63;
    int lr = lane & 15, g = lane >> 4;
    int wm = w >> 1, wn = w & 1;
    int kz = blockIdx.x >> 8;                    // 0..3
    int mn = blockIdx.x & 255;                   // 256 mn-tiles
    mn = (mn & 7) * 32 + (mn >> 3);              // XCD-chunked
    int m0 = (mn >> 2) * 64, n0 = (mn & 3) * 64;
    int kbeg = kz * 512;
    int trow = tid >> 3, tcol = (tid & 7) << 3;

    f32x4 acc[2][2] = {};

    for (int kb = kbeg; kb < kbeg + 512; kb += 64) {
        if (kb != kbeg) __syncthreads();
        #pragma unroll
        for (int r = 0; r < 2; r++) {
            int row = r * 32 + trow;
            uint4 va = *(const uint4*)(A + (size_t)(m0 + row) * Kk + kb + tcol);
            *(uint4*)(As + row * LDA + tcol) = va;
            uint4 vb = *(const uint4*)(Bw + (size_t)(n0 + row) * Kk + kb + tcol);
            *(uint4*)(Bs + row * LDA + tcol) = vb;
        }
        __syncthreads();
        #pragma unroll
        for (int kk = 0; kk < 2; kk++) {
            short8 af[2], bfr[2];
            #pragma unroll
            for (int mi = 0; mi < 2; mi++)
                af[mi] = *(const short8*)(As + (wm * 32 + mi * 16 + lr) * LDA + kk * 32 + g * 8);
            #pragma unroll
            for (int ni = 0; ni < 2; ni++)
                bfr[ni] = *(const short8*)(Bs + (wn * 32 + ni * 16 + lr) * LDA + kk * 32 + g * 8);
            #pragma unroll
            for (int mi = 0; mi < 2; mi++)
                #pragma unroll
                for (int ni = 0; ni < 2; ni++)
                    acc[mi][ni] = __builtin_amdgcn_mfma_f32_16x16x32_bf16(af[mi], bfr[ni], acc[mi][ni], 0, 0, 0);
        }
    }

    float* Cz = Cp + (size_t)kz * NR * Nn;
    #pragma unroll
    for (int ni = 0; ni < 2; ni++) {
        int col = n0 + wn * 32 + ni * 16 + lr;
        float bi = (kz == 0) ? bias[col] : 0.0f;
        #pragma unroll
        for (int mi = 0; mi < 2; mi++)
            #pragma unroll
            for (int jj = 0; jj < 4; jj++) {
                int row = m0 + wm * 32 + mi * 16 + g * 4 + jj;
                Cz[(size_t)row * Nn + col] = acc[mi][ni][jj] + bi;
            }
    }
}

// ---------------- MFMA flash attention (HD=32), bf16 in, bf16 out ----------------
// grid = 512, XCD-chunked (each XCD owns 4 whole heads -> K/V L2-resident).
// 4 waves, 16 q-rows each. swapped QK^T; padded-linear LDS; natural-domain softmax.

__global__ __launch_bounds__(256) void k_attn(const u16* __restrict__ qp, int qs,
                                              const u16* __restrict__ kvp, int ks, int koff, int voff,
                                              const float* __restrict__ addv, u16* __restrict__ out) {
    __shared__ __align__(16) u16 Kl[128 * 32];       // [key][d] linear
    __shared__ __align__(16) u16 VTl[32 * 136];      // [d][key] padded linear
    __shared__ __align__(16) u16 Pl[4 * 16 * 136];   // per-wave [q][key] padded linear
    __shared__ float Al[128];

    int tid = threadIdx.x, w = tid >> 6, lane = tid & 63;
    int lr = lane & 15, g = lane >> 4;
    int blk = blockIdx.x;
    blk = (blk & 7) * 64 + (blk >> 3);               // XCD-chunked (512 = 8 x 64)
    int qb = blk & 15, h = (blk >> 4) & 7, b = blk >> 7;
    int q0 = qb * 64 + w * 16;
    const float QS = 0.17677669529663687f;   // 1/sqrt(32)

    short8 qf = *(const short8*)(qp + (size_t)(b * S_ + q0 + lr) * qs + h * 32 + g * 8);

    f32x4 o0 = {0.f, 0.f, 0.f, 0.f}, o1 = {0.f, 0.f, 0.f, 0.f};
    float m_run = -3.0e38f, l_run = 0.0f;
    float sreg[8][4];
    u16* Pw = Pl + w * 16 * 136;

    int key_t = tid >> 1, dh = (tid & 1) * 16;
    const u16* kbase = kvp + (size_t)(b * S_) * ks;

    for (int kb = 0; kb < 8; kb++) {
        {
            const u16* srck = kbase + (size_t)(kb * 128 + key_t) * ks + koff + h * 32 + dh;
            uint4 a0 = *(const uint4*)srck;
            uint4 a1 = *(const uint4*)(srck + 8);
            *(uint4*)(Kl + key_t * 32 + dh) = a0;
            *(uint4*)(Kl + key_t * 32 + dh + 8) = a1;
            const u16* srcv = kbase + (size_t)(kb * 128 + key_t) * ks + voff + h * 32 + dh;
            union { uint4 v[2]; u16 s[16]; } vu;
            vu.v[0] = *(const uint4*)srcv; vu.v[1] = *(const uint4*)(srcv + 8);
            #pragma unroll
            for (int i = 0; i < 16; i++) VTl[(dh + i) * 136 + key_t] = vu.s[i];
            if (tid < 128) Al[tid] = addv[b * S_ + kb * 128 + tid];
        }
        __syncthreads();

        #pragma unroll
        for (int t = 0; t < 8; t++) {
            short8 kf = *(const short8*)(Kl + (t * 16 + lr) * 32 + g * 8);
            f32x4 z = {0.f, 0.f, 0.f, 0.f};
            f32x4 st = __builtin_amdgcn_mfma_f32_16x16x32_bf16(kf, qf, z, 0, 0, 0);
            #pragma unroll
            for (int jj = 0; jj < 4; jj++) sreg[t][jj] = st[jj] * QS + Al[t * 16 + g * 4 + jj];
        }

        float mb = -3.0e38f;
        #pragma unroll
        for (int t = 0; t < 8; t++)
            #pragma unroll
            for (int jj = 0; jj < 4; jj++) mb = fmaxf(mb, sreg[t][jj]);
        mb = fmaxf(mb, __shfl_xor(mb, 16, 64));
        mb = fmaxf(mb, __shfl_xor(mb, 32, 64));
        float mnew = fmaxf(m_run, mb);
        float sc = __expf(m_run - mnew);
        float ls = 0.f;
        #pragma unroll
        for (int t = 0; t < 8; t++)
            #pragma unroll
            for (int jj = 0; jj < 4; jj++) {
                float p = __expf(sreg[t][jj] - mnew);
                sreg[t][jj] = p; ls += p;
            }
        ls += __shfl_xor(ls, 16, 64); ls += __shfl_xor(ls, 32, 64);
        l_run = l_run * sc + ls; m_run = mnew;
        #pragma unroll
        for (int jj = 0; jj < 4; jj++) {
            float scj = __shfl(sc, 20 * g + jj, 64);
            o0[jj] *= scj; o1[jj] *= scj;
        }

        #pragma unroll
        for (int t = 0; t < 8; t++) {
            u32 u0 = (u32)f2bf(sreg[t][0]) | ((u32)f2bf(sreg[t][1]) << 16);
            u32 u1 = (u32)f2bf(sreg[t][2]) | ((u32)f2bf(sreg[t][3]) << 16);
            *(uint2*)(Pw + lr * 136 + t * 16 + g * 4) = make_uint2(u0, u1);
        }

        #pragma unroll
        for (int c = 0; c < 4; c++) {
            short8 pa = *(const short8*)(Pw + lr * 136 + c * 32 + g * 8);
            short8 v0 = *(const short8*)(VTl + lr * 136 + c * 32 + g * 8);
            short8 v1 = *(const short8*)(VTl + (16 + lr) * 136 + c * 32 + g * 8);
            o0 = __builtin_amdgcn_mfma_f32_16x16x32_bf16(pa, v0, o0, 0, 0, 0);
            o1 = __builtin_amdgcn_mfma_f32_16x16x32_bf16(pa, v1, o1, 0, 0, 0);
        }
        __syncthreads();
    }

    float li = 1.0f / l_run;
    #pragma unroll
    for (int jj = 0; jj < 4; jj++) {
        float lij = __shfl(li, 20 * g + jj, 64);
        int r = q0 + g * 4 + jj;
        u16* op = out + (size_t)(b * S_ + r) * 256 + h * 32;
        op[lr]      = f2bf(o0[jj] * lij);
        op[16 + lr] = f2bf(o1[jj] * lij);
    }
}

// ---------------- host orchestration ----------------

extern "C" void kernel_launch(void* const* d_in, const int* in_sizes, int n_in,
                              void* d_out, int out_size, void* d_ws, size_t ws_size,
                              hipStream_t stream) {
    const int* x                = (const int*)d_in[0];
    const unsigned char* mask   = (const unsigned char*)d_in[1];
    const float* codebook       = (const float*)d_in[2];
    const float* pos            = (const float*)d_in[3];
    const float* enc_qkv_w = (const float*)d_in[4];  const float* enc_qkv_b = (const float*)d_in[5];
    const float* enc_out_w = (const float*)d_in[6];  const float* enc_out_b = (const float*)d_in[7];
    const float* enc_ff1_w = (const float*)d_in[8];  const float* enc_ff1_b = (const float*)d_in[9];
    const float* enc_ff2_w = (const float*)d_in[10]; const float* enc_ff2_b = (const float*)d_in[11];
    const float* enc_ln1_g = (const float*)d_in[12]; const float* enc_ln1_b = (const float*)d_in[13];
    const float* enc_ln2_g = (const float*)d_in[14]; const float* enc_ln2_b = (const float*)d_in[15];
    const float* dec_sa_qkv_w = (const float*)d_in[16]; const float* dec_sa_qkv_b = (const float*)d_in[17];
    const float* dec_sa_out_w = (const float*)d_in[18]; const float* dec_sa_out_b = (const float*)d_in[19];
    const float* dec_ca_qkv_w = (const float*)d_in[20]; const float* dec_ca_qkv_b = (const float*)d_in[21];
    const float* dec_ca_out_w = (const float*)d_in[22]; const float* dec_ca_out_b = (const float*)d_in[23];
    const float* dec_ff1_w = (const float*)d_in[24]; const float* dec_ff1_b = (const float*)d_in[25];
    const float* dec_ff2_w = (const float*)d_in[26]; const float* dec_ff2_b = (const float*)d_in[27];
    const float* dec_ln1_g = (const float*)d_in[28]; const float* dec_ln1_b = (const float*)d_in[29];
    const float* dec_ln2_g = (const float*)d_in[30]; const float* dec_ln2_b = (const float*)d_in[31];
    const float* dec_ln3_g = (const float*)d_in[32]; const float* dec_ln3_b = (const float*)d_in[33];

    char* ws = (char*)d_ws; size_t off = 0;
    auto alloc = [&](size_t b) { char* p = ws + off; off += (b + 255) & ~(size_t)255; return p; };

    // bf16 weights — CONTIGUOUS block in k_conv_all segment order
    u16* w_eqkv  = (u16*)alloc((size_t)786432 * 2);
    u16* w_eout  = (u16*)alloc((size_t)262144 * 2);
    u16* w_eff1  = (u16*)alloc((size_t)2097152 * 2);
    u16* w_eff2  = (u16*)alloc((size_t)2097152 * 2);
    u16* w_dsaq  = (u16*)alloc((size_t)786432 * 2);
    u16* w_dsao  = (u16*)alloc((size_t)262144 * 2);
    u16* w_dcaq  = (u16*)alloc((size_t)786432 * 2);
    u16* w_dcao  = (u16*)alloc((size_t)262144 * 2);
    u16* w_dff1  = (u16*)alloc((size_t)2097152 * 2);
    u16* w_dff2  = (u16*)alloc((size_t)2097152 * 2);
    // persistent activations
    float* h_f   = (float*)alloc((size_t)NR * D_ * 4);
    u16*   h_b   = (u16*)  alloc((size_t)NR * D_ * 2);
    float* ctx_f = (float*)alloc((size_t)NR * D_ * 4);
    u16*   ctx_b = (u16*)  alloc((size_t)NR * D_ * 2);
    float* dd_f  = (float*)alloc((size_t)NR * D_ * 4);
    u16*   dd_b  = (u16*)  alloc((size_t)NR * D_ * 2);
    float* gem_f = (float*)alloc((size_t)NR * 256 * 4);
    float* gem_p = (float*)alloc((size_t)4 * NR * 256 * 4);   // split-K partials (16MB)
    u16*   attno = (u16*)  alloc((size_t)NR * 256 * 2);
    float* addv  = (float*)alloc((size_t)NR * 4);
    float* addvz = (float*)alloc((size_t)NR * 4);
    // 16MB scratch, time-shared: enc {qkv_b | ffh_b}; dec {v_b -> qca,kvca | ffh_b}
    u16* scr = (u16*)alloc((size_t)NR * 2048 * 2);
    u16* qkv_b = scr;
    u16* ffh_b = scr;
    u16* v_b   = scr;
    u16* qca_b = scr;
    u16* kvca_b = scr + (size_t)NR * 256;
    (void)in_sizes; (void)n_in;

    // tripwire: if workspace too small, emit sentinel 1000.0 -> absmax ~1000
    if (off > ws_size) {
        k_fillf<<<(out_size + 255) / 256, 256, 0, stream>>>((float*)d_out, out_size, 1000.0f);
        return;
    }

    k_conv_all<<<2048, 256, 0, stream>>>(enc_qkv_w, enc_out_w, enc_ff1_w, enc_ff2_w,
                                         dec_sa_qkv_w, dec_sa_out_w, dec_ca_qkv_w, dec_ca_out_w,
                                         dec_ff1_w, dec_ff2_w, w_eqkv);
    k_addv<<<16, 256, 0, stream>>>(mask, addv, addvz);
    k_embed<<<1024, 256, 0, stream>>>(x, codebook, pos, h_f, h_b);

    // ---- encoder ----
    for (int l = 0; l < 4; l++) {
        const u16* inb = l ? ctx_b : h_b;
        const float* inf = l ? ctx_f : h_f;
        k_gemm<128,128,false,true><<<192, 256, 0, stream>>>(inb, w_eqkv + (size_t)l*196608,
            enc_qkv_b + l*768, nullptr, qkv_b, 768, 256);
        k_attn<<<512, 256, 0, stream>>>(qkv_b, 768, qkv_b, 768, 256, 512, addv, attno);
        k_gemm<64,64,false,false><<<256, 256, 0, stream>>>(attno, w_eout + (size_t)l*65536,
            enc_out_b + l*256, gem_f, nullptr, 256, 256);
        k_ln<<<1024, 256, 0, stream>>>(inf, gem_f, enc_ln1_g + l*256, enc_ln1_b + l*256, ctx_f, ctx_b);
        k_gemm<128,128,true,true><<<512, 256, 0, stream>>>(ctx_b, w_eff1 + (size_t)l*524288,
            enc_ff1_b + l*2048, nullptr, ffh_b, 2048, 256);
        k_gemm_sk4<<<1024, 256, 0, stream>>>(ffh_b, w_eff2 + (size_t)l*524288,
            enc_ff2_b + l*256, gem_p);
        k_ln4<<<1024, 256, 0, stream>>>(ctx_f, gem_p, enc_ln2_g + l*256, enc_ln2_b + l*256, ctx_f, ctx_b);
    }

    // ---- decoder ----
    for (int l = 0; l < 4; l++) {
        const u16* inb = l ? dd_b : h_b;
        const float* inf = l ? dd_f : h_f;
        // self-attn degenerates to out_proj(v_proj(x))
        k_gemm<64,64,false,true><<<256, 256, 0, stream>>>(inb, w_dsaq + (size_t)l*196608 + 131072,
            dec_sa_qkv_b + l*768 + 512, nullptr, v_b, 256, 256);
        k_gemm<64,64,false,false><<<256, 256, 0, stream>>>(v_b, w_dsao + (size_t)l*65536,
            dec_sa_out_b + l*256, gem_f, nullptr, 256, 256);
        k_ln<<<1024, 256, 0, stream>>>(inf, gem_f, dec_ln1_g + l*256, dec_ln1_b + l*256, dd_f, dd_b);
        // cross-attn (v_b dead now; qca/kvca reuse scratch)
        k_gemm<64,64,false,true><<<256, 256, 0, stream>>>(dd_b, w_dcaq + (size_t)l*196608,
            dec_ca_qkv_b + l*768, nullptr, qca_b, 256, 256);
        k_gemm<64,64,false,true><<<512, 256, 0, stream>>>(ctx_b, w_dcaq + (size_t)l*196608 + 65536,
            dec_ca_qkv_b + l*768 + 256, nullptr, kvca_b, 512, 256);
        k_attn<<<512, 256, 0, stream>>>(qca_b, 256, kvca_b, 512, 0, 256, addvz, attno);
        k_gemm<64,64,false,false><<<256, 256, 0, stream>>>(attno, w_dcao + (size_t)l*65536,
            dec_ca_out_b + l*256, gem_f, nullptr, 256, 256);
        k_ln<<<1024, 256, 0, stream>>>(dd_f, gem_f, dec_ln2_g + l*256, dec_ln2_b + l*256, dd_f, dd_b);
        // FFN (qca/kvca dead; ffh reuses scratch)
        k_gemm<128,128,true,true><<<512, 256, 0, stream>>>(dd_b, w_dff1 + (size_t)l*524288,
            dec_ff1_b + l*2048, nullptr, ffh_b, 2048, 256);
        k_gemm_sk4<<<1024, 256, 0, stream>>>(ffh_b, w_dff2 + (size_t)l*524288,
            dec_ff2_b + l*256, gem_p);
        // final layer: f32 master goes straight to d_out (reference output dtype is float32)
        k_ln4<<<1024, 256, 0, stream>>>(dd_f, gem_p, dec_ln3_g + l*256, dec_ln3_b + l*256,
                                        (l == 3) ? (float*)d_out : dd_f, dd_b);
    }
}

// Round 11
// 620.886 us; speedup vs baseline: 1.7863x; 1.0410x over previous
//
#include <hip/hip_runtime.h>

typedef unsigned short u16;
typedef unsigned int   u32;
typedef short short8 __attribute__((ext_vector_type(8)));
typedef float f32x4  __attribute__((ext_vector_type(4)));

#define DEV static __device__ __forceinline__

static constexpr int S_ = 1024;   // seq len
static constexpr int D_ = 256;    // model dim
static constexpr int NR = 4096;   // B*S rows

DEV u16 f2bf(float x) {
    u32 u = __float_as_uint(x);
    return (u16)((u + 0x7FFFu + ((u >> 16) & 1u)) >> 16);
}
DEV float bf2f(u16 s) { return __uint_as_float(((u32)s) << 16); }

// ---------------- elementwise / prep kernels ----------------

__global__ __launch_bounds__(256) void k_fillf(float* __restrict__ o, int n, float v) {
    int i = blockIdx.x * 256 + threadIdx.x;
    if (i < n) o[i] = v;
}

// all-weights f32->bf16 conversion in ONE dispatch; dst contiguous in alloc order.
__global__ __launch_bounds__(256) void k_conv_all(
        const float* __restrict__ s0, const float* __restrict__ s1, const float* __restrict__ s2,
        const float* __restrict__ s3, const float* __restrict__ s4, const float* __restrict__ s5,
        const float* __restrict__ s6, const float* __restrict__ s7, const float* __restrict__ s8,
        const float* __restrict__ s9, u16* __restrict__ dst) {
    constexpr int c0 = 786432/4,            c1 = c0 + 262144/4,  c2 = c1 + 2097152/4,
                  c3 = c2 + 2097152/4,      c4 = c3 + 786432/4,  c5 = c4 + 262144/4,
                  c6 = c5 + 786432/4,       c7 = c6 + 262144/4,  c8 = c7 + 2097152/4,
                  c9 = c8 + 2097152/4;
    for (int i = blockIdx.x * 256 + threadIdx.x; i < c9; i += gridDim.x * 256) {
        const float* src; int base;
        if      (i < c0) { src = s0; base = 0;  }
        else if (i < c1) { src = s1; base = c0; }
        else if (i < c2) { src = s2; base = c1; }
        else if (i < c3) { src = s3; base = c2; }
        else if (i < c4) { src = s4; base = c3; }
        else if (i < c5) { src = s5; base = c4; }
        else if (i < c6) { src = s6; base = c5; }
        else if (i < c7) { src = s7; base = c6; }
        else if (i < c8) { src = s8; base = c7; }
        else             { src = s9; base = c8; }
        float4 v = ((const float4*)src)[i - base];
        ushort4 o; o.x = f2bf(v.x); o.y = f2bf(v.y); o.z = f2bf(v.z); o.w = f2bf(v.w);
        ((ushort4*)dst)[i] = o;
    }
}

// combined dec self-attn weights: W_sa[l] = out_w[l] @ wv[l] (f32 accumulate -> bf16),
// b_sa[l] = out_w[l] @ bv[l] + out_b[l] (f32). One block per (layer, output row n).
__global__ __launch_bounds__(256) void k_wsa(const float* __restrict__ qkvw, const float* __restrict__ qkvb,
                                             const float* __restrict__ outw, const float* __restrict__ outb,
                                             u16* __restrict__ wsa, float* __restrict__ bsa) {
    int l = blockIdx.x >> 8, n = blockIdx.x & 255, t = threadIdx.x;
    const float* wv = qkvw + (size_t)l * 196608 + 131072;   // [256][256] rows 512..767
    const float* bv = qkvb + l * 768 + 512;
    const float* wo = outw + (size_t)l * 65536 + n * 256;
    float acc = 0.0f, pb = 0.0f;
    for (int j = 0; j < 256; j++) {
        float woj = wo[j];
        acc = fmaf(woj, wv[j * 256 + t], acc);    // coalesced across t
        pb  = fmaf(woj, bv[j], pb);
    }
    wsa[(size_t)l * 65536 + n * 256 + t] = f2bf(acc);
    if (t == 0) bsa[l * 256 + n] = pb + outb[l * 256 + n];
}

// embed + mask->addend fused
__global__ __launch_bounds__(256) void k_embed(const int* __restrict__ xx,
                                               const float* __restrict__ cb,
                                               const float* __restrict__ pos,
                                               const unsigned char* __restrict__ mask,
                                               float* __restrict__ hf, u16* __restrict__ hb,
                                               float* __restrict__ av, float* __restrict__ avz) {
    int wid = threadIdx.x >> 6, lane = threadIdx.x & 63;
    int row = blockIdx.x * 4 + wid;         // 0..4095
    int sp = row & (S_ - 1);
    int tok = xx[row];
    float4 c = ((const float4*)(cb + (size_t)tok * D_))[lane];
    float4 p = ((const float4*)(pos + (size_t)sp * D_))[lane];
    float4 s; s.x = c.x + p.x; s.y = c.y + p.y; s.z = c.z + p.z; s.w = c.w + p.w;
    ((float4*)(hf + (size_t)row * D_))[lane] = s;
    ushort4 o; o.x = f2bf(s.x); o.y = f2bf(s.y); o.z = f2bf(s.z); o.w = f2bf(s.w);
    ((ushort4*)(hb + (size_t)row * D_))[lane] = o;
    if (lane == 0) { av[row] = mask[row] ? -2.0e9f : 0.0f; avz[row] = 0.0f; }
}

// residual + layernorm; writes f32 master and bf16 copy
__global__ __launch_bounds__(256) void k_ln(const float* __restrict__ x, const float* __restrict__ y,
                                            const float* __restrict__ gg, const float* __restrict__ bb,
                                            float* __restrict__ of, u16* __restrict__ ob) {
    int wid = threadIdx.x >> 6, lane = threadIdx.x & 63;
    int row = blockIdx.x * 4 + wid;
    float4 xv = ((const float4*)(x + (size_t)row * D_))[lane];
    float4 yv = ((const float4*)(y + (size_t)row * D_))[lane];
    float4 s; s.x = xv.x + yv.x; s.y = xv.y + yv.y; s.z = xv.z + yv.z; s.w = xv.w + yv.w;
    float sum = s.x + s.y + s.z + s.w;
    float sq  = s.x * s.x + s.y * s.y + s.z * s.z + s.w * s.w;
    #pragma unroll
    for (int m = 1; m < 64; m <<= 1) { sum += __shfl_xor(sum, m, 64); sq += __shfl_xor(sq, m, 64); }
    float mean = sum * (1.0f / 256.0f);
    float var  = sq * (1.0f / 256.0f) - mean * mean;
    float rs = rsqrtf(var + 1e-5f);
    float4 gv = ((const float4*)gg)[lane];
    float4 bv = ((const float4*)bb)[lane];
    float4 o;
    o.x = (s.x - mean) * rs * gv.x + bv.x;
    o.y = (s.y - mean) * rs * gv.y + bv.y;
    o.z = (s.z - mean) * rs * gv.z + bv.z;
    o.w = (s.w - mean) * rs * gv.w + bv.w;
    ((float4*)(of + (size_t)row * D_))[lane] = o;
    ushort4 ub; ub.x = f2bf(o.x); ub.y = f2bf(o.y); ub.z = f2bf(o.z); ub.w = f2bf(o.w);
    ((ushort4*)(ob + (size_t)row * D_))[lane] = ub;
}

// residual + sum-4-partials + layernorm (used after split-K ff2)
__global__ __launch_bounds__(256) void k_ln4(const float* __restrict__ x, const float* __restrict__ yp,
                                             const float* __restrict__ gg, const float* __restrict__ bb,
                                             float* __restrict__ of, u16* __restrict__ ob) {
    int wid = threadIdx.x >> 6, lane = threadIdx.x & 63;
    int row = blockIdx.x * 4 + wid;
    float4 xv = ((const float4*)(x + (size_t)row * D_))[lane];
    float4 s = xv;
    #pragma unroll
    for (int kz = 0; kz < 4; kz++) {
        float4 yv = ((const float4*)(yp + (size_t)kz * NR * D_ + (size_t)row * D_))[lane];
        s.x += yv.x; s.y += yv.y; s.z += yv.z; s.w += yv.w;
    }
    float sum = s.x + s.y + s.z + s.w;
    float sq  = s.x * s.x + s.y * s.y + s.z * s.z + s.w * s.w;
    #pragma unroll
    for (int m = 1; m < 64; m <<= 1) { sum += __shfl_xor(sum, m, 64); sq += __shfl_xor(sq, m, 64); }
    float mean = sum * (1.0f / 256.0f);
    float var  = sq * (1.0f / 256.0f) - mean * mean;
    float rs = rsqrtf(var + 1e-5f);
    float4 gv = ((const float4*)gg)[lane];
    float4 bv = ((const float4*)bb)[lane];
    float4 o;
    o.x = (s.x - mean) * rs * gv.x + bv.x;
    o.y = (s.y - mean) * rs * gv.y + bv.y;
    o.z = (s.z - mean) * rs * gv.z + bv.z;
    o.w = (s.w - mean) * rs * gv.w + bv.w;
    ((float4*)(of + (size_t)row * D_))[lane] = o;
    ushort4 ub; ub.x = f2bf(o.x); ub.y = f2bf(o.y); ub.z = f2bf(o.z); ub.w = f2bf(o.w);
    ((ushort4*)(ob + (size_t)row * D_))[lane] = ub;
}

// ---------------- MFMA GEMM (round-5 structure):  C = A @ W^T + bias ----------------

template <int BM, int BN, bool RELU, bool OBF16>
__global__ __launch_bounds__(256) void k_gemm(const u16* __restrict__ A, const u16* __restrict__ Bw,
                                              const float* __restrict__ bias,
                                              float* __restrict__ Cf, u16* __restrict__ Cb,
                                              int Nn, int Kk) {
    constexpr int FM = BM / 32, FN = BN / 32;
    constexpr int LDA = 72;
    __shared__ __align__(16) u16 As[BM * LDA];
    __shared__ __align__(16) u16 Bs[BN * LDA];
    int tid = threadIdx.x, w = tid >> 6, lane = tid & 63;
    int lr = lane & 15, g = lane >> 4;
    int wm = w >> 1, wn = w & 1;
    int nbn = Nn / BN;
    int bid = blockIdx.x, nwg = gridDim.x;
    if ((nwg & 7) == 0) bid = (bid & 7) * (nwg >> 3) + (bid >> 3);
    int m0 = (bid / nbn) * BM, n0 = (bid % nbn) * BN;
    int trow = tid >> 3, tcol = (tid & 7) << 3;

    f32x4 acc[FM][FN] = {};

    for (int kb = 0; kb < Kk; kb += 64) {
        if (kb) __syncthreads();
        #pragma unroll
        for (int r = 0; r < BM / 32; r++) {
            int row = r * 32 + trow;
            uint4 v = *(const uint4*)(A + (size_t)(m0 + row) * Kk + kb + tcol);
            *(uint4*)(As + row * LDA + tcol) = v;
        }
        #pragma unroll
        for (int r = 0; r < BN / 32; r++) {
            int row = r * 32 + trow;
            uint4 v = *(const uint4*)(Bw + (size_t)(n0 + row) * Kk + kb + tcol);
            *(uint4*)(Bs + row * LDA + tcol) = v;
        }
        __syncthreads();
        #pragma unroll
        for (int kk = 0; kk < 2; kk++) {
            short8 af[FM], bfr[FN];
            #pragma unroll
            for (int mi = 0; mi < FM; mi++)
                af[mi] = *(const short8*)(As + (wm * (BM / 2) + mi * 16 + lr) * LDA + kk * 32 + g * 8);
            #pragma unroll
            for (int ni = 0; ni < FN; ni++)
                bfr[ni] = *(const short8*)(Bs + (wn * (BN / 2) + ni * 16 + lr) * LDA + kk * 32 + g * 8);
            #pragma unroll
            for (int mi = 0; mi < FM; mi++)
                #pragma unroll
                for (int ni = 0; ni < FN; ni++)
                    acc[mi][ni] = __builtin_amdgcn_mfma_f32_16x16x32_bf16(af[mi], bfr[ni], acc[mi][ni], 0, 0, 0);
        }
    }

    #pragma unroll
    for (int ni = 0; ni < FN; ni++) {
        int col = n0 + wn * (BN / 2) + ni * 16 + lr;
        float bi = bias[col];
        #pragma unroll
        for (int mi = 0; mi < FM; mi++) {
            #pragma unroll
            for (int jj = 0; jj < 4; jj++) {
                int row = m0 + wm * (BM / 2) + mi * 16 + g * 4 + jj;
                float v = acc[mi][ni][jj] + bi;
                if (RELU) v = fmaxf(v, 0.0f);
                if (OBF16) Cb[(size_t)row * Nn + col] = f2bf(v);
                else       Cf[(size_t)row * Nn + col] = v;
            }
        }
    }
}

// ff2 split-K=4: grid 1024 = 256 mn-tiles x 4 kz; f32 partials, bias folded into kz==0.
__global__ __launch_bounds__(256) void k_gemm_sk4(const u16* __restrict__ A, const u16* __restrict__ Bw,
                                                  const float* __restrict__ bias, float* __restrict__ Cp) {
    constexpr int LDA = 72, Nn = 256, Kk = 2048;
    __shared__ __align__(16) u16 As[64 * LDA];
    __shared__ __align__(16) u16 Bs[64 * LDA];
    int tid = threadIdx.x, w = tid >> 6, lane = tid & 63;
    int lr = lane & 15, g = lane >> 4;
    int wm = w >> 1, wn = w & 1;
    int kz = blockIdx.x >> 8;
    int mn = blockIdx.x & 255;
    mn = (mn & 7) * 32 + (mn >> 3);
    int m0 = (mn >> 2) * 64, n0 = (mn & 3) * 64;
    int kbeg = kz * 512;
    int trow = tid >> 3, tcol = (tid & 7) << 3;

    f32x4 acc[2][2] = {};

    for (int kb = kbeg; kb < kbeg + 512; kb += 64) {
        if (kb != kbeg) __syncthreads();
        #pragma unroll
        for (int r = 0; r < 2; r++) {
            int row = r * 32 + trow;
            uint4 va = *(const uint4*)(A + (size_t)(m0 + row) * Kk + kb + tcol);
            *(uint4*)(As + row * LDA + tcol) = va;
            uint4 vb = *(const uint4*)(Bw + (size_t)(n0 + row) * Kk + kb + tcol);
            *(uint4*)(Bs + row * LDA + tcol) = vb;
        }
        __syncthreads();
        #pragma unroll
        for (int kk = 0; kk < 2; kk++) {
            short8 af[2], bfr[2];
            #pragma unroll
            for (int mi = 0; mi < 2; mi++)
                af[mi] = *(const short8*)(As + (wm * 32 + mi * 16 + lr) * LDA + kk * 32 + g * 8);
            #pragma unroll
            for (int ni = 0; ni < 2; ni++)
                bfr[ni] = *(const short8*)(Bs + (wn * 32 + ni * 16 + lr) * LDA + kk * 32 + g * 8);
            #pragma unroll
            for (int mi = 0; mi < 2; mi++)
                #pragma unroll
                for (int ni = 0; ni < 2; ni++)
                    acc[mi][ni] = __builtin_amdgcn_mfma_f32_16x16x32_bf16(af[mi], bfr[ni], acc[mi][ni], 0, 0, 0);
        }
    }

    float* Cz = Cp + (size_t)kz * NR * Nn;
    #pragma unroll
    for (int ni = 0; ni < 2; ni++) {
        int col = n0 + wn * 32 + ni * 16 + lr;
        float bi = (kz == 0) ? bias[col] : 0.0f;
        #pragma unroll
        for (int mi = 0; mi < 2; mi++)
            #pragma unroll
            for (int jj = 0; jj < 4; jj++) {
                int row = m0 + wm * 32 + mi * 16 + g * 4 + jj;
                Cz[(size_t)row * Nn + col] = acc[mi][ni][jj] + bi;
            }
    }
}

// ---------------- MFMA flash attention (HD=32) with K/V prefetch dbuf ----------------
// grid = 512, XCD-chunked. ld(t+1) issued after QK^T so HBM latency hides under
// softmax+P+PV; double-buffered Kl/VTl/Al; 2 barriers/iter (same as before).

__global__ __launch_bounds__(256) void k_attn(const u16* __restrict__ qp, int qs,
                                              const u16* __restrict__ kvp, int ks, int koff, int voff,
                                              const float* __restrict__ addv, u16* __restrict__ out) {
    __shared__ __align__(16) u16 Kl[2][128 * 32];
    __shared__ __align__(16) u16 VTl[2][32 * 136];
    __shared__ __align__(16) u16 Pl[4 * 16 * 136];
    __shared__ float Al[2][128];

    int tid = threadIdx.x, w = tid >> 6, lane = tid & 63;
    int lr = lane & 15, g = lane >> 4;
    int blk = blockIdx.x;
    blk = (blk & 7) * 64 + (blk >> 3);
    int qb = blk & 15, h = (blk >> 4) & 7, b = blk >> 7;
    int q0 = qb * 64 + w * 16;
    const float QS = 0.17677669529663687f;

    short8 qf = *(const short8*)(qp + (size_t)(b * S_ + q0 + lr) * qs + h * 32 + g * 8);

    f32x4 o0 = {0.f, 0.f, 0.f, 0.f}, o1 = {0.f, 0.f, 0.f, 0.f};
    float m_run = -3.0e38f, l_run = 0.0f;
    float sreg[8][4];
    u16* Pw = Pl + w * 16 * 136;

    int key_t = tid >> 1, dh = (tid & 1) * 16;
    const u16* kbase = kvp + (size_t)(b * S_) * ks;

    uint4 ka0, ka1;
    union { uint4 v[2]; u16 s[16]; } vu;
    float alv = 0.0f;
    auto ldregs = [&](int kb) {
        const u16* srck = kbase + (size_t)(kb * 128 + key_t) * ks + koff + h * 32 + dh;
        ka0 = *(const uint4*)srck;
        ka1 = *(const uint4*)(srck + 8);
        const u16* srcv = kbase + (size_t)(kb * 128 + key_t) * ks + voff + h * 32 + dh;
        vu.v[0] = *(const uint4*)srcv;
        vu.v[1] = *(const uint4*)(srcv + 8);
        if (tid < 128) alv = addv[b * S_ + kb * 128 + tid];
    };
    auto stbuf = [&](int buf) {
        *(uint4*)(&Kl[buf][key_t * 32 + dh])     = ka0;
        *(uint4*)(&Kl[buf][key_t * 32 + dh + 8]) = ka1;
        #pragma unroll
        for (int i = 0; i < 16; i++) VTl[buf][(dh + i) * 136 + key_t] = vu.s[i];
        if (tid < 128) Al[buf][tid] = alv;
    };

    ldregs(0); stbuf(0);
    int cur = 0;
    for (int kb = 0; kb < 8; kb++) {
        __syncthreads();                          // buf[cur] visible

        #pragma unroll
        for (int t = 0; t < 8; t++) {
            short8 kf = *(const short8*)(&Kl[cur][(t * 16 + lr) * 32 + g * 8]);
            f32x4 z = {0.f, 0.f, 0.f, 0.f};
            f32x4 st = __builtin_amdgcn_mfma_f32_16x16x32_bf16(kf, qf, z, 0, 0, 0);
            #pragma unroll
            for (int jj = 0; jj < 4; jj++) sreg[t][jj] = st[jj] * QS + Al[cur][t * 16 + g * 4 + jj];
        }

        if (kb < 7) ldregs(kb + 1);               // latency hides under softmax+P+PV

        float mb = -3.0e38f;
        #pragma unroll
        for (int t = 0; t < 8; t++)
            #pragma unroll
            for (int jj = 0; jj < 4; jj++) mb = fmaxf(mb, sreg[t][jj]);
        mb = fmaxf(mb, __shfl_xor(mb, 16, 64));
        mb = fmaxf(mb, __shfl_xor(mb, 32, 64));
        float mnew = fmaxf(m_run, mb);
        float sc = __expf(m_run - mnew);
        float ls = 0.f;
        #pragma unroll
        for (int t = 0; t < 8; t++)
            #pragma unroll
            for (int jj = 0; jj < 4; jj++) {
                float p = __expf(sreg[t][jj] - mnew);
                sreg[t][jj] = p; ls += p;
            }
        ls += __shfl_xor(ls, 16, 64); ls += __shfl_xor(ls, 32, 64);
        l_run = l_run * sc + ls; m_run = mnew;
        #pragma unroll
        for (int jj = 0; jj < 4; jj++) {
            float scj = __shfl(sc, 20 * g + jj, 64);
            o0[jj] *= scj; o1[jj] *= scj;
        }

        #pragma unroll
        for (int t = 0; t < 8; t++) {
            u32 u0 = (u32)f2bf(sreg[t][0]) | ((u32)f2bf(sreg[t][1]) << 16);
            u32 u1 = (u32)f2bf(sreg[t][2]) | ((u32)f2bf(sreg[t][3]) << 16);
            *(uint2*)(Pw + lr * 136 + t * 16 + g * 4) = make_uint2(u0, u1);
        }

        #pragma unroll
        for (int c = 0; c < 4; c++) {
            short8 pa = *(const short8*)(Pw + lr * 136 + c * 32 + g * 8);
            short8 v0 = *(const short8*)(&VTl[cur][lr * 136 + c * 32 + g * 8]);
            short8 v1 = *(const short8*)(&VTl[cur][(16 + lr) * 136 + c * 32 + g * 8]);
            o0 = __builtin_amdgcn_mfma_f32_16x16x32_bf16(pa, v0, o0, 0, 0, 0);
            o1 = __builtin_amdgcn_mfma_f32_16x16x32_bf16(pa, v1, o1, 0, 0, 0);
        }

        __syncthreads();                          // compute on buf[cur] done
        if (kb < 7) stbuf(cur ^ 1);               // safe: cur^1 readers retired last iter
        cur ^= 1;
    }

    float li = 1.0f / l_run;
    #pragma unroll
    for (int jj = 0; jj < 4; jj++) {
        float lij = __shfl(li, 20 * g + jj, 64);
        int r = q0 + g * 4 + jj;
        u16* op = out + (size_t)(b * S_ + r) * 256 + h * 32;
        op[lr]      = f2bf(o0[jj] * lij);
        op[16 + lr] = f2bf(o1[jj] * lij);
    }
}

// ---------------- host orchestration ----------------

extern "C" void kernel_launch(void* const* d_in, const int* in_sizes, int n_in,
                              void* d_out, int out_size, void* d_ws, size_t ws_size,
                              hipStream_t stream) {
    const int* x                = (const int*)d_in[0];
    const unsigned char* mask   = (const unsigned char*)d_in[1];
    const float* codebook       = (const float*)d_in[2];
    const float* pos            = (const float*)d_in[3];
    const float* enc_qkv_w = (const float*)d_in[4];  const float* enc_qkv_b = (const float*)d_in[5];
    const float* enc_out_w = (const float*)d_in[6];  const float* enc_out_b = (const float*)d_in[7];
    const float* enc_ff1_w = (const float*)d_in[8];  const float* enc_ff1_b = (const float*)d_in[9];
    const float* enc_ff2_w = (const float*)d_in[10]; const float* enc_ff2_b = (const float*)d_in[11];
    const float* enc_ln1_g = (const float*)d_in[12]; const float* enc_ln1_b = (const float*)d_in[13];
    const float* enc_ln2_g = (const float*)d_in[14]; const float* enc_ln2_b = (const float*)d_in[15];
    const float* dec_sa_qkv_w = (const float*)d_in[16]; const float* dec_sa_qkv_b = (const float*)d_in[17];
    const float* dec_sa_out_w = (const float*)d_in[18]; const float* dec_sa_out_b = (const float*)d_in[19];
    const float* dec_ca_qkv_w = (const float*)d_in[20]; const float* dec_ca_qkv_b = (const float*)d_in[21];
    const float* dec_ca_out_w = (const float*)d_in[22]; const float* dec_ca_out_b = (const float*)d_in[23];
    const float* dec_ff1_w = (const float*)d_in[24]; const float* dec_ff1_b = (const float*)d_in[25];
    const float* dec_ff2_w = (const float*)d_in[26]; const float* dec_ff2_b = (const float*)d_in[27];
    const float* dec_ln1_g = (const float*)d_in[28]; const float* dec_ln1_b = (const float*)d_in[29];
    const float* dec_ln2_g = (const float*)d_in[30]; const float* dec_ln2_b = (const float*)d_in[31];
    const float* dec_ln3_g = (const float*)d_in[32]; const float* dec_ln3_b = (const float*)d_in[33];

    char* ws = (char*)d_ws; size_t off = 0;
    auto alloc = [&](size_t b) { char* p = ws + off; off += (b + 255) & ~(size_t)255; return p; };

    // bf16 weights — CONTIGUOUS block in k_conv_all segment order
    u16* w_eqkv  = (u16*)alloc((size_t)786432 * 2);
    u16* w_eout  = (u16*)alloc((size_t)262144 * 2);
    u16* w_eff1  = (u16*)alloc((size_t)2097152 * 2);
    u16* w_eff2  = (u16*)alloc((size_t)2097152 * 2);
    u16* w_dsaq  = (u16*)alloc((size_t)786432 * 2);
    u16* w_dsao  = (u16*)alloc((size_t)262144 * 2);
    u16* w_dcaq  = (u16*)alloc((size_t)786432 * 2);
    u16* w_dcao  = (u16*)alloc((size_t)262144 * 2);
    u16* w_dff1  = (u16*)alloc((size_t)2097152 * 2);
    u16* w_dff2  = (u16*)alloc((size_t)2097152 * 2);
    // combined dec self-attn weights
    u16*   wsa   = (u16*)  alloc((size_t)4 * 65536 * 2);
    float* bsa   = (float*)alloc((size_t)4 * 256 * 4);
    // persistent activations
    float* h_f   = (float*)alloc((size_t)NR * D_ * 4);
    u16*   h_b   = (u16*)  alloc((size_t)NR * D_ * 2);
    float* ctx_f = (float*)alloc((size_t)NR * D_ * 4);
    u16*   ctx_b = (u16*)  alloc((size_t)NR * D_ * 2);
    float* dd_f  = (float*)alloc((size_t)NR * D_ * 4);
    u16*   dd_b  = (u16*)  alloc((size_t)NR * D_ * 2);
    float* gem_f = (float*)alloc((size_t)NR * 256 * 4);
    float* gem_p = (float*)alloc((size_t)4 * NR * 256 * 4);   // split-K partials (16MB)
    u16*   attno = (u16*)  alloc((size_t)NR * 256 * 2);
    float* addv  = (float*)alloc((size_t)NR * 4);
    float* addvz = (float*)alloc((size_t)NR * 4);
    // 16MB scratch, time-shared
    u16* scr = (u16*)alloc((size_t)NR * 2048 * 2);
    u16* qkv_b = scr;
    u16* ffh_b = scr;
    u16* qca_b = scr;
    u16* kvca_b = scr + (size_t)NR * 256;
    (void)in_sizes; (void)n_in;

    if (off > ws_size) {
        k_fillf<<<(out_size + 255) / 256, 256, 0, stream>>>((float*)d_out, out_size, 1000.0f);
        return;
    }

    k_conv_all<<<2048, 256, 0, stream>>>(enc_qkv_w, enc_out_w, enc_ff1_w, enc_ff2_w,
                                         dec_sa_qkv_w, dec_sa_out_w, dec_ca_qkv_w, dec_ca_out_w,
                                         dec_ff1_w, dec_ff2_w, w_eqkv);
    k_wsa<<<1024, 256, 0, stream>>>(dec_sa_qkv_w, dec_sa_qkv_b, dec_sa_out_w, dec_sa_out_b, wsa, bsa);
    k_embed<<<1024, 256, 0, stream>>>(x, codebook, pos, mask, h_f, h_b, addv, addvz);

    // ---- encoder ----
    for (int l = 0; l < 4; l++) {
        const u16* inb = l ? ctx_b : h_b;
        const float* inf = l ? ctx_f : h_f;
        k_gemm<128,128,false,true><<<192, 256, 0, stream>>>(inb, w_eqkv + (size_t)l*196608,
            enc_qkv_b + l*768, nullptr, qkv_b, 768, 256);
        k_attn<<<512, 256, 0, stream>>>(qkv_b, 768, qkv_b, 768, 256, 512, addv, attno);
        k_gemm<64,64,false,false><<<256, 256, 0, stream>>>(attno, w_eout + (size_t)l*65536,
            enc_out_b + l*256, gem_f, nullptr, 256, 256);
        k_ln<<<1024, 256, 0, stream>>>(inf, gem_f, enc_ln1_g + l*256, enc_ln1_b + l*256, ctx_f, ctx_b);
        k_gemm<128,128,true,true><<<512, 256, 0, stream>>>(ctx_b, w_eff1 + (size_t)l*524288,
            enc_ff1_b + l*2048, nullptr, ffh_b, 2048, 256);
        k_gemm_sk4<<<1024, 256, 0, stream>>>(ffh_b, w_eff2 + (size_t)l*524288,
            enc_ff2_b + l*256, gem_p);
        k_ln4<<<1024, 256, 0, stream>>>(ctx_f, gem_p, enc_ln2_g + l*256, enc_ln2_b + l*256, ctx_f, ctx_b);
    }

    // ---- decoder ----
    for (int l = 0; l < 4; l++) {
        const u16* inb = l ? dd_b : h_b;
        const float* inf = l ? dd_f : h_f;
        // self-attn == single GEMM with combined weight (out_w @ v_w)
        k_gemm<64,64,false,false><<<256, 256, 0, stream>>>(inb, wsa + (size_t)l*65536,
            bsa + l*256, gem_f, nullptr, 256, 256);
        k_ln<<<1024, 256, 0, stream>>>(inf, gem_f, dec_ln1_g + l*256, dec_ln1_b + l*256, dd_f, dd_b);
        // cross-attn
        k_gemm<64,64,false,true><<<256, 256, 0, stream>>>(dd_b, w_dcaq + (size_t)l*196608,
            dec_ca_qkv_b + l*768, nullptr, qca_b, 256, 256);
        k_gemm<64,64,false,true><<<512, 256, 0, stream>>>(ctx_b, w_dcaq + (size_t)l*196608 + 65536,
            dec_ca_qkv_b + l*768 + 256, nullptr, kvca_b, 512, 256);
        k_attn<<<512, 256, 0, stream>>>(qca_b, 256, kvca_b, 512, 0, 256, addvz, attno);
        k_gemm<64,64,false,false><<<256, 256, 0, stream>>>(attno, w_dcao + (size_t)l*65536,
            dec_ca_out_b + l*256, gem_f, nullptr, 256, 256);
        k_ln<<<1024, 256, 0, stream>>>(dd_f, gem_f, dec_ln2_g + l*256, dec_ln2_b + l*256, dd_f, dd_b);
        // FFN
        k_gemm<128,128,true,true><<<512, 256, 0, stream>>>(dd_b, w_dff1 + (size_t)l*524288,
            dec_ff1_b + l*2048, nullptr, ffh_b, 2048, 256);
        k_gemm_sk4<<<1024, 256, 0, stream>>>(ffh_b, w_dff2 + (size_t)l*524288,
            dec_ff2_b + l*256, gem_p);
        k_ln4<<<1024, 256, 0, stream>>>(dd_f, gem_p, dec_ln3_g + l*256, dec_ln3_b + l*256,
                                        (l == 3) ? (float*)d_out : dd_f, dd_b);
    }
}

// Round 12
// 601.333 us; speedup vs baseline: 1.8444x; 1.0325x over previous
//
#include <hip/hip_runtime.h>

typedef unsigned short u16;
typedef unsigned int   u32;
typedef short short8 __attribute__((ext_vector_type(8)));
typedef float f32x4  __attribute__((ext_vector_type(4)));

#define DEV static __device__ __forceinline__

static constexpr int S_ = 1024;   // seq len
static constexpr int D_ = 256;    // model dim
static constexpr int NR = 4096;   // B*S rows

DEV u16 f2bf(float x) {
    u32 u = __float_as_uint(x);
    return (u16)((u + 0x7FFFu + ((u >> 16) & 1u)) >> 16);
}
DEV float bf2f(u16 s) { return __uint_as_float(((u32)s) << 16); }

// ---------------- elementwise / prep kernels ----------------

__global__ __launch_bounds__(256) void k_fillf(float* __restrict__ o, int n, float v) {
    int i = blockIdx.x * 256 + threadIdx.x;
    if (i < n) o[i] = v;
}

// all-weights f32->bf16 conversion in ONE dispatch; dst contiguous in alloc order.
__global__ __launch_bounds__(256) void k_conv_all(
        const float* __restrict__ s0, const float* __restrict__ s1, const float* __restrict__ s2,
        const float* __restrict__ s3, const float* __restrict__ s4, const float* __restrict__ s5,
        const float* __restrict__ s6, const float* __restrict__ s7, const float* __restrict__ s8,
        const float* __restrict__ s9, u16* __restrict__ dst) {
    constexpr int c0 = 786432/4,            c1 = c0 + 262144/4,  c2 = c1 + 2097152/4,
                  c3 = c2 + 2097152/4,      c4 = c3 + 786432/4,  c5 = c4 + 262144/4,
                  c6 = c5 + 786432/4,       c7 = c6 + 262144/4,  c8 = c7 + 2097152/4,
                  c9 = c8 + 2097152/4;
    for (int i = blockIdx.x * 256 + threadIdx.x; i < c9; i += gridDim.x * 256) {
        const float* src; int base;
        if      (i < c0) { src = s0; base = 0;  }
        else if (i < c1) { src = s1; base = c0; }
        else if (i < c2) { src = s2; base = c1; }
        else if (i < c3) { src = s3; base = c2; }
        else if (i < c4) { src = s4; base = c3; }
        else if (i < c5) { src = s5; base = c4; }
        else if (i < c6) { src = s6; base = c5; }
        else if (i < c7) { src = s7; base = c6; }
        else if (i < c8) { src = s8; base = c7; }
        else             { src = s9; base = c8; }
        float4 v = ((const float4*)src)[i - base];
        ushort4 o; o.x = f2bf(v.x); o.y = f2bf(v.y); o.z = f2bf(v.z); o.w = f2bf(v.w);
        ((ushort4*)dst)[i] = o;
    }
}

// combined dec self-attn weights: W_sa[l] = out_w[l] @ wv[l], b_sa[l] = out_w[l] @ bv[l] + out_b[l]
__global__ __launch_bounds__(256) void k_wsa(const float* __restrict__ qkvw, const float* __restrict__ qkvb,
                                             const float* __restrict__ outw, const float* __restrict__ outb,
                                             u16* __restrict__ wsa, float* __restrict__ bsa) {
    int l = blockIdx.x >> 8, n = blockIdx.x & 255, t = threadIdx.x;
    const float* wv = qkvw + (size_t)l * 196608 + 131072;
    const float* bv = qkvb + l * 768 + 512;
    const float* wo = outw + (size_t)l * 65536 + n * 256;
    float acc = 0.0f, pb = 0.0f;
    for (int j = 0; j < 256; j++) {
        float woj = wo[j];
        acc = fmaf(woj, wv[j * 256 + t], acc);
        pb  = fmaf(woj, bv[j], pb);
    }
    wsa[(size_t)l * 65536 + n * 256 + t] = f2bf(acc);
    if (t == 0) bsa[l * 256 + n] = pb + outb[l * 256 + n];
}

// embed + mask->addend fused
__global__ __launch_bounds__(256) void k_embed(const int* __restrict__ xx,
                                               const float* __restrict__ cb,
                                               const float* __restrict__ pos,
                                               const unsigned char* __restrict__ mask,
                                               float* __restrict__ hf, u16* __restrict__ hb,
                                               float* __restrict__ av, float* __restrict__ avz) {
    int wid = threadIdx.x >> 6, lane = threadIdx.x & 63;
    int row = blockIdx.x * 4 + wid;
    int sp = row & (S_ - 1);
    int tok = xx[row];
    float4 c = ((const float4*)(cb + (size_t)tok * D_))[lane];
    float4 p = ((const float4*)(pos + (size_t)sp * D_))[lane];
    float4 s; s.x = c.x + p.x; s.y = c.y + p.y; s.z = c.z + p.z; s.w = c.w + p.w;
    ((float4*)(hf + (size_t)row * D_))[lane] = s;
    ushort4 o; o.x = f2bf(s.x); o.y = f2bf(s.y); o.z = f2bf(s.z); o.w = f2bf(s.w);
    ((ushort4*)(hb + (size_t)row * D_))[lane] = o;
    if (lane == 0) { av[row] = mask[row] ? -2.0e9f : 0.0f; avz[row] = 0.0f; }
}

// residual + layernorm; writes f32 master and bf16 copy
__global__ __launch_bounds__(256) void k_ln(const float* __restrict__ x, const float* __restrict__ y,
                                            const float* __restrict__ gg, const float* __restrict__ bb,
                                            float* __restrict__ of, u16* __restrict__ ob) {
    int wid = threadIdx.x >> 6, lane = threadIdx.x & 63;
    int row = blockIdx.x * 4 + wid;
    float4 xv = ((const float4*)(x + (size_t)row * D_))[lane];
    float4 yv = ((const float4*)(y + (size_t)row * D_))[lane];
    float4 s; s.x = xv.x + yv.x; s.y = xv.y + yv.y; s.z = xv.z + yv.z; s.w = xv.w + yv.w;
    float sum = s.x + s.y + s.z + s.w;
    float sq  = s.x * s.x + s.y * s.y + s.z * s.z + s.w * s.w;
    #pragma unroll
    for (int m = 1; m < 64; m <<= 1) { sum += __shfl_xor(sum, m, 64); sq += __shfl_xor(sq, m, 64); }
    float mean = sum * (1.0f / 256.0f);
    float var  = sq * (1.0f / 256.0f) - mean * mean;
    float rs = rsqrtf(var + 1e-5f);
    float4 gv = ((const float4*)gg)[lane];
    float4 bv = ((const float4*)bb)[lane];
    float4 o;
    o.x = (s.x - mean) * rs * gv.x + bv.x;
    o.y = (s.y - mean) * rs * gv.y + bv.y;
    o.z = (s.z - mean) * rs * gv.z + bv.z;
    o.w = (s.w - mean) * rs * gv.w + bv.w;
    ((float4*)(of + (size_t)row * D_))[lane] = o;
    ushort4 ub; ub.x = f2bf(o.x); ub.y = f2bf(o.y); ub.z = f2bf(o.z); ub.w = f2bf(o.w);
    ((ushort4*)(ob + (size_t)row * D_))[lane] = ub;
}

// residual + sum-4-bf16-partials + layernorm (after split-K ff2)
__global__ __launch_bounds__(256) void k_ln4(const float* __restrict__ x, const u16* __restrict__ yp,
                                             const float* __restrict__ gg, const float* __restrict__ bb,
                                             float* __restrict__ of, u16* __restrict__ ob) {
    int wid = threadIdx.x >> 6, lane = threadIdx.x & 63;
    int row = blockIdx.x * 4 + wid;
    float4 xv = ((const float4*)(x + (size_t)row * D_))[lane];
    float4 s = xv;
    #pragma unroll
    for (int kz = 0; kz < 4; kz++) {
        ushort4 yv = ((const ushort4*)(yp + (size_t)kz * NR * D_ + (size_t)row * D_))[lane];
        s.x += bf2f(yv.x); s.y += bf2f(yv.y); s.z += bf2f(yv.z); s.w += bf2f(yv.w);
    }
    float sum = s.x + s.y + s.z + s.w;
    float sq  = s.x * s.x + s.y * s.y + s.z * s.z + s.w * s.w;
    #pragma unroll
    for (int m = 1; m < 64; m <<= 1) { sum += __shfl_xor(sum, m, 64); sq += __shfl_xor(sq, m, 64); }
    float mean = sum * (1.0f / 256.0f);
    float var  = sq * (1.0f / 256.0f) - mean * mean;
    float rs = rsqrtf(var + 1e-5f);
    float4 gv = ((const float4*)gg)[lane];
    float4 bv = ((const float4*)bb)[lane];
    float4 o;
    o.x = (s.x - mean) * rs * gv.x + bv.x;
    o.y = (s.y - mean) * rs * gv.y + bv.y;
    o.z = (s.z - mean) * rs * gv.z + bv.z;
    o.w = (s.w - mean) * rs * gv.w + bv.w;
    ((float4*)(of + (size_t)row * D_))[lane] = o;
    ushort4 ub; ub.x = f2bf(o.x); ub.y = f2bf(o.y); ub.z = f2bf(o.z); ub.w = f2bf(o.w);
    ((ushort4*)(ob + (size_t)row * D_))[lane] = ub;
}

// ---------------- MFMA GEMM (round-5 structure):  C = A @ W^T + bias ----------------

template <int BM, int BN, bool RELU, bool OBF16>
__global__ __launch_bounds__(256) void k_gemm(const u16* __restrict__ A, const u16* __restrict__ Bw,
                                              const float* __restrict__ bias,
                                              float* __restrict__ Cf, u16* __restrict__ Cb,
                                              int Nn, int Kk) {
    constexpr int FM = BM / 32, FN = BN / 32;
    constexpr int LDA = 72;
    __shared__ __align__(16) u16 As[BM * LDA];
    __shared__ __align__(16) u16 Bs[BN * LDA];
    int tid = threadIdx.x, w = tid >> 6, lane = tid & 63;
    int lr = lane & 15, g = lane >> 4;
    int wm = w >> 1, wn = w & 1;
    int nbn = Nn / BN;
    int bid = blockIdx.x, nwg = gridDim.x;
    if ((nwg & 7) == 0) bid = (bid & 7) * (nwg >> 3) + (bid >> 3);
    int m0 = (bid / nbn) * BM, n0 = (bid % nbn) * BN;
    int trow = tid >> 3, tcol = (tid & 7) << 3;

    f32x4 acc[FM][FN] = {};

    for (int kb = 0; kb < Kk; kb += 64) {
        if (kb) __syncthreads();
        #pragma unroll
        for (int r = 0; r < BM / 32; r++) {
            int row = r * 32 + trow;
            uint4 v = *(const uint4*)(A + (size_t)(m0 + row) * Kk + kb + tcol);
            *(uint4*)(As + row * LDA + tcol) = v;
        }
        #pragma unroll
        for (int r = 0; r < BN / 32; r++) {
            int row = r * 32 + trow;
            uint4 v = *(const uint4*)(Bw + (size_t)(n0 + row) * Kk + kb + tcol);
            *(uint4*)(Bs + row * LDA + tcol) = v;
        }
        __syncthreads();
        #pragma unroll
        for (int kk = 0; kk < 2; kk++) {
            short8 af[FM], bfr[FN];
            #pragma unroll
            for (int mi = 0; mi < FM; mi++)
                af[mi] = *(const short8*)(As + (wm * (BM / 2) + mi * 16 + lr) * LDA + kk * 32 + g * 8);
            #pragma unroll
            for (int ni = 0; ni < FN; ni++)
                bfr[ni] = *(const short8*)(Bs + (wn * (BN / 2) + ni * 16 + lr) * LDA + kk * 32 + g * 8);
            #pragma unroll
            for (int mi = 0; mi < FM; mi++)
                #pragma unroll
                for (int ni = 0; ni < FN; ni++)
                    acc[mi][ni] = __builtin_amdgcn_mfma_f32_16x16x32_bf16(af[mi], bfr[ni], acc[mi][ni], 0, 0, 0);
        }
    }

    #pragma unroll
    for (int ni = 0; ni < FN; ni++) {
        int col = n0 + wn * (BN / 2) + ni * 16 + lr;
        float bi = bias[col];
        #pragma unroll
        for (int mi = 0; mi < FM; mi++) {
            #pragma unroll
            for (int jj = 0; jj < 4; jj++) {
                int row = m0 + wm * (BM / 2) + mi * 16 + g * 4 + jj;
                float v = acc[mi][ni][jj] + bi;
                if (RELU) v = fmaxf(v, 0.0f);
                if (OBF16) Cb[(size_t)row * Nn + col] = f2bf(v);
                else       Cf[(size_t)row * Nn + col] = v;
            }
        }
    }
}

// merged qca+kvca: grid 768 (XCD-chunked). Blocks 0..255: qca (N=256); 256..767: kvca (N=512).
// 64^2 tile, K=256; both bf16 outputs.
__global__ __launch_bounds__(256) void k_gemm2(const u16* __restrict__ A0, const u16* __restrict__ W0,
                                               const float* __restrict__ b0, u16* __restrict__ C0,
                                               const u16* __restrict__ A1, const u16* __restrict__ W1,
                                               const float* __restrict__ b1, u16* __restrict__ C1) {
    constexpr int LDA = 72, Kk = 256;
    __shared__ __align__(16) u16 As[64 * LDA];
    __shared__ __align__(16) u16 Bs[64 * LDA];
    int tid = threadIdx.x, w = tid >> 6, lane = tid & 63;
    int lr = lane & 15, g = lane >> 4;
    int wm = w >> 1, wn = w & 1;
    int bid = blockIdx.x;
    bid = (bid & 7) * 96 + (bid >> 3);          // XCD-chunked over 768
    const u16 *A, *Bw; const float* bias; u16* Cb; int Nn, nbn, seg;
    if (bid < 256) { A = A0; Bw = W0; bias = b0; Cb = C0; Nn = 256; nbn = 4; seg = bid; }
    else           { A = A1; Bw = W1; bias = b1; Cb = C1; Nn = 512; nbn = 8; seg = bid - 256; }
    int m0 = (seg / nbn) * 64, n0 = (seg % nbn) * 64;
    int trow = tid >> 3, tcol = (tid & 7) << 3;

    f32x4 acc[2][2] = {};

    for (int kb = 0; kb < Kk; kb += 64) {
        if (kb) __syncthreads();
        #pragma unroll
        for (int r = 0; r < 2; r++) {
            int row = r * 32 + trow;
            uint4 va = *(const uint4*)(A + (size_t)(m0 + row) * Kk + kb + tcol);
            *(uint4*)(As + row * LDA + tcol) = va;
            uint4 vb = *(const uint4*)(Bw + (size_t)(n0 + row) * Kk + kb + tcol);
            *(uint4*)(Bs + row * LDA + tcol) = vb;
        }
        __syncthreads();
        #pragma unroll
        for (int kk = 0; kk < 2; kk++) {
            short8 af[2], bfr[2];
            #pragma unroll
            for (int mi = 0; mi < 2; mi++)
                af[mi] = *(const short8*)(As + (wm * 32 + mi * 16 + lr) * LDA + kk * 32 + g * 8);
            #pragma unroll
            for (int ni = 0; ni < 2; ni++)
                bfr[ni] = *(const short8*)(Bs + (wn * 32 + ni * 16 + lr) * LDA + kk * 32 + g * 8);
            #pragma unroll
            for (int mi = 0; mi < 2; mi++)
                #pragma unroll
                for (int ni = 0; ni < 2; ni++)
                    acc[mi][ni] = __builtin_amdgcn_mfma_f32_16x16x32_bf16(af[mi], bfr[ni], acc[mi][ni], 0, 0, 0);
        }
    }

    #pragma unroll
    for (int ni = 0; ni < 2; ni++) {
        int col = n0 + wn * 32 + ni * 16 + lr;
        float bi = bias[col];
        #pragma unroll
        for (int mi = 0; mi < 2; mi++)
            #pragma unroll
            for (int jj = 0; jj < 4; jj++) {
                int row = m0 + wm * 32 + mi * 16 + g * 4 + jj;
                Cb[(size_t)row * Nn + col] = f2bf(acc[mi][ni][jj] + bi);
            }
    }
}

// ff2 split-K=4: grid 1024 = 256 mn-tiles x 4 kz; bf16 partials, bias folded into kz==0.
__global__ __launch_bounds__(256) void k_gemm_sk4(const u16* __restrict__ A, const u16* __restrict__ Bw,
                                                  const float* __restrict__ bias, u16* __restrict__ Cp) {
    constexpr int LDA = 72, Nn = 256, Kk = 2048;
    __shared__ __align__(16) u16 As[64 * LDA];
    __shared__ __align__(16) u16 Bs[64 * LDA];
    int tid = threadIdx.x, w = tid >> 6, lane = tid & 63;
    int lr = lane & 15, g = lane >> 4;
    int wm = w >> 1, wn = w & 1;
    int kz = blockIdx.x >> 8;
    int mn = blockIdx.x & 255;
    mn = (mn & 7) * 32 + (mn >> 3);
    int m0 = (mn >> 2) * 64, n0 = (mn & 3) * 64;
    int kbeg = kz * 512;
    int trow = tid >> 3, tcol = (tid & 7) << 3;

    f32x4 acc[2][2] = {};

    for (int kb = kbeg; kb < kbeg + 512; kb += 64) {
        if (kb != kbeg) __syncthreads();
        #pragma unroll
        for (int r = 0; r < 2; r++) {
            int row = r * 32 + trow;
            uint4 va = *(const uint4*)(A + (size_t)(m0 + row) * Kk + kb + tcol);
            *(uint4*)(As + row * LDA + tcol) = va;
            uint4 vb = *(const uint4*)(Bw + (size_t)(n0 + row) * Kk + kb + tcol);
            *(uint4*)(Bs + row * LDA + tcol) = vb;
        }
        __syncthreads();
        #pragma unroll
        for (int kk = 0; kk < 2; kk++) {
            short8 af[2], bfr[2];
            #pragma unroll
            for (int mi = 0; mi < 2; mi++)
                af[mi] = *(const short8*)(As + (wm * 32 + mi * 16 + lr) * LDA + kk * 32 + g * 8);
            #pragma unroll
            for (int ni = 0; ni < 2; ni++)
                bfr[ni] = *(const short8*)(Bs + (wn * 32 + ni * 16 + lr) * LDA + kk * 32 + g * 8);
            #pragma unroll
            for (int mi = 0; mi < 2; mi++)
                #pragma unroll
                for (int ni = 0; ni < 2; ni++)
                    acc[mi][ni] = __builtin_amdgcn_mfma_f32_16x16x32_bf16(af[mi], bfr[ni], acc[mi][ni], 0, 0, 0);
        }
    }

    u16* Cz = Cp + (size_t)kz * NR * Nn;
    #pragma unroll
    for (int ni = 0; ni < 2; ni++) {
        int col = n0 + wn * 32 + ni * 16 + lr;
        float bi = (kz == 0) ? bias[col] : 0.0f;
        #pragma unroll
        for (int mi = 0; mi < 2; mi++)
            #pragma unroll
            for (int jj = 0; jj < 4; jj++) {
                int row = m0 + wm * 32 + mi * 16 + g * 4 + jj;
                Cz[(size_t)row * Nn + col] = f2bf(acc[mi][ni][jj] + bi);
            }
    }
}

// ---------------- MFMA flash attention (HD=32), exp2-domain softmax, K/V dbuf ----------------

__global__ __launch_bounds__(256) void k_attn(const u16* __restrict__ qp, int qs,
                                              const u16* __restrict__ kvp, int ks, int koff, int voff,
                                              const float* __restrict__ addv, u16* __restrict__ out) {
    __shared__ __align__(16) u16 Kl[2][128 * 32];
    __shared__ __align__(16) u16 VTl[2][32 * 136];
    __shared__ __align__(16) u16 Pl[4 * 16 * 136];
    __shared__ float Al[2][128];

    int tid = threadIdx.x, w = tid >> 6, lane = tid & 63;
    int lr = lane & 15, g = lane >> 4;
    int blk = blockIdx.x;
    blk = (blk & 7) * 64 + (blk >> 3);
    int qb = blk & 15, h = (blk >> 4) & 7, b = blk >> 7;
    int q0 = qb * 64 + w * 16;
    const float QS2 = 0.17677669529663687f * 1.4426950408889634f;   // 1/sqrt(32) * log2(e)

    short8 qf = *(const short8*)(qp + (size_t)(b * S_ + q0 + lr) * qs + h * 32 + g * 8);

    f32x4 o0 = {0.f, 0.f, 0.f, 0.f}, o1 = {0.f, 0.f, 0.f, 0.f};
    float m_run = -3.0e38f, l_run = 0.0f;
    float sreg[8][4];
    u16* Pw = Pl + w * 16 * 136;

    int key_t = tid >> 1, dh = (tid & 1) * 16;
    const u16* kbase = kvp + (size_t)(b * S_) * ks;

    uint4 ka0, ka1;
    union { uint4 v[2]; u16 s[16]; } vu;
    float alv = 0.0f;
    auto ldregs = [&](int kb) {
        const u16* srck = kbase + (size_t)(kb * 128 + key_t) * ks + koff + h * 32 + dh;
        ka0 = *(const uint4*)srck;
        ka1 = *(const uint4*)(srck + 8);
        const u16* srcv = kbase + (size_t)(kb * 128 + key_t) * ks + voff + h * 32 + dh;
        vu.v[0] = *(const uint4*)srcv;
        vu.v[1] = *(const uint4*)(srcv + 8);
        if (tid < 128) alv = addv[b * S_ + kb * 128 + tid];
    };
    auto stbuf = [&](int buf) {
        *(uint4*)(&Kl[buf][key_t * 32 + dh])     = ka0;
        *(uint4*)(&Kl[buf][key_t * 32 + dh + 8]) = ka1;
        #pragma unroll
        for (int i = 0; i < 16; i++) VTl[buf][(dh + i) * 136 + key_t] = vu.s[i];
        if (tid < 128) Al[buf][tid] = alv;
    };

    ldregs(0); stbuf(0);
    int cur = 0;
    for (int kb = 0; kb < 8; kb++) {
        __syncthreads();

        #pragma unroll
        for (int t = 0; t < 8; t++) {
            short8 kf = *(const short8*)(&Kl[cur][(t * 16 + lr) * 32 + g * 8]);
            f32x4 z = {0.f, 0.f, 0.f, 0.f};
            f32x4 st = __builtin_amdgcn_mfma_f32_16x16x32_bf16(kf, qf, z, 0, 0, 0);
            #pragma unroll
            for (int jj = 0; jj < 4; jj++) sreg[t][jj] = st[jj] * QS2 + Al[cur][t * 16 + g * 4 + jj];
        }

        if (kb < 7) ldregs(kb + 1);

        float mb = -3.0e38f;
        #pragma unroll
        for (int t = 0; t < 8; t++)
            #pragma unroll
            for (int jj = 0; jj < 4; jj++) mb = fmaxf(mb, sreg[t][jj]);
        mb = fmaxf(mb, __shfl_xor(mb, 16, 64));
        mb = fmaxf(mb, __shfl_xor(mb, 32, 64));
        float mnew = fmaxf(m_run, mb);
        float sc = __builtin_amdgcn_exp2f(m_run - mnew);
        float ls = 0.f;
        #pragma unroll
        for (int t = 0; t < 8; t++)
            #pragma unroll
            for (int jj = 0; jj < 4; jj++) {
                float p = __builtin_amdgcn_exp2f(sreg[t][jj] - mnew);
                sreg[t][jj] = p; ls += p;
            }
        ls += __shfl_xor(ls, 16, 64); ls += __shfl_xor(ls, 32, 64);
        l_run = l_run * sc + ls; m_run = mnew;
        #pragma unroll
        for (int jj = 0; jj < 4; jj++) {
            float scj = __shfl(sc, 20 * g + jj, 64);
            o0[jj] *= scj; o1[jj] *= scj;
        }

        #pragma unroll
        for (int t = 0; t < 8; t++) {
            u32 u0 = (u32)f2bf(sreg[t][0]) | ((u32)f2bf(sreg[t][1]) << 16);
            u32 u1 = (u32)f2bf(sreg[t][2]) | ((u32)f2bf(sreg[t][3]) << 16);
            *(uint2*)(Pw + lr * 136 + t * 16 + g * 4) = make_uint2(u0, u1);
        }

        #pragma unroll
        for (int c = 0; c < 4; c++) {
            short8 pa = *(const short8*)(Pw + lr * 136 + c * 32 + g * 8);
            short8 v0 = *(const short8*)(&VTl[cur][lr * 136 + c * 32 + g * 8]);
            short8 v1 = *(const short8*)(&VTl[cur][(16 + lr) * 136 + c * 32 + g * 8]);
            o0 = __builtin_amdgcn_mfma_f32_16x16x32_bf16(pa, v0, o0, 0, 0, 0);
            o1 = __builtin_amdgcn_mfma_f32_16x16x32_bf16(pa, v1, o1, 0, 0, 0);
        }

        __syncthreads();
        if (kb < 7) stbuf(cur ^ 1);
        cur ^= 1;
    }

    float li = 1.0f / l_run;
    #pragma unroll
    for (int jj = 0; jj < 4; jj++) {
        float lij = __shfl(li, 20 * g + jj, 64);
        int r = q0 + g * 4 + jj;
        u16* op = out + (size_t)(b * S_ + r) * 256 + h * 32;
        op[lr]      = f2bf(o0[jj] * lij);
        op[16 + lr] = f2bf(o1[jj] * lij);
    }
}

// ---------------- host orchestration ----------------

extern "C" void kernel_launch(void* const* d_in, const int* in_sizes, int n_in,
                              void* d_out, int out_size, void* d_ws, size_t ws_size,
                              hipStream_t stream) {
    const int* x                = (const int*)d_in[0];
    const unsigned char* mask   = (const unsigned char*)d_in[1];
    const float* codebook       = (const float*)d_in[2];
    const float* pos            = (const float*)d_in[3];
    const float* enc_qkv_w = (const float*)d_in[4];  const float* enc_qkv_b = (const float*)d_in[5];
    const float* enc_out_w = (const float*)d_in[6];  const float* enc_out_b = (const float*)d_in[7];
    const float* enc_ff1_w = (const float*)d_in[8];  const float* enc_ff1_b = (const float*)d_in[9];
    const float* enc_ff2_w = (const float*)d_in[10]; const float* enc_ff2_b = (const float*)d_in[11];
    const float* enc_ln1_g = (const float*)d_in[12]; const float* enc_ln1_b = (const float*)d_in[13];
    const float* enc_ln2_g = (const float*)d_in[14]; const float* enc_ln2_b = (const float*)d_in[15];
    const float* dec_sa_qkv_w = (const float*)d_in[16]; const float* dec_sa_qkv_b = (const float*)d_in[17];
    const float* dec_sa_out_w = (const float*)d_in[18]; const float* dec_sa_out_b = (const float*)d_in[19];
    const float* dec_ca_qkv_w = (const float*)d_in[20]; const float* dec_ca_qkv_b = (const float*)d_in[21];
    const float* dec_ca_out_w = (const float*)d_in[22]; const float* dec_ca_out_b = (const float*)d_in[23];
    const float* dec_ff1_w = (const float*)d_in[24]; const float* dec_ff1_b = (const float*)d_in[25];
    const float* dec_ff2_w = (const float*)d_in[26]; const float* dec_ff2_b = (const float*)d_in[27];
    const float* dec_ln1_g = (const float*)d_in[28]; const float* dec_ln1_b = (const float*)d_in[29];
    const float* dec_ln2_g = (const float*)d_in[30]; const float* dec_ln2_b = (const float*)d_in[31];
    const float* dec_ln3_g = (const float*)d_in[32]; const float* dec_ln3_b = (const float*)d_in[33];

    char* ws = (char*)d_ws; size_t off = 0;
    auto alloc = [&](size_t b) { char* p = ws + off; off += (b + 255) & ~(size_t)255; return p; };

    u16* w_eqkv  = (u16*)alloc((size_t)786432 * 2);
    u16* w_eout  = (u16*)alloc((size_t)262144 * 2);
    u16* w_eff1  = (u16*)alloc((size_t)2097152 * 2);
    u16* w_eff2  = (u16*)alloc((size_t)2097152 * 2);
    u16* w_dsaq  = (u16*)alloc((size_t)786432 * 2);
    u16* w_dsao  = (u16*)alloc((size_t)262144 * 2);
    u16* w_dcaq  = (u16*)alloc((size_t)786432 * 2);
    u16* w_dcao  = (u16*)alloc((size_t)262144 * 2);
    u16* w_dff1  = (u16*)alloc((size_t)2097152 * 2);
    u16* w_dff2  = (u16*)alloc((size_t)2097152 * 2);
    u16*   wsa   = (u16*)  alloc((size_t)4 * 65536 * 2);
    float* bsa   = (float*)alloc((size_t)4 * 256 * 4);
    float* h_f   = (float*)alloc((size_t)NR * D_ * 4);
    u16*   h_b   = (u16*)  alloc((size_t)NR * D_ * 2);
    float* ctx_f = (float*)alloc((size_t)NR * D_ * 4);
    u16*   ctx_b = (u16*)  alloc((size_t)NR * D_ * 2);
    float* dd_f  = (float*)alloc((size_t)NR * D_ * 4);
    u16*   dd_b  = (u16*)  alloc((size_t)NR * D_ * 2);
    float* gem_f = (float*)alloc((size_t)NR * 256 * 4);
    u16*   gem_p = (u16*)  alloc((size_t)4 * NR * 256 * 2);   // bf16 split-K partials (8MB)
    u16*   attno = (u16*)  alloc((size_t)NR * 256 * 2);
    float* addv  = (float*)alloc((size_t)NR * 4);
    float* addvz = (float*)alloc((size_t)NR * 4);
    u16* scr = (u16*)alloc((size_t)NR * 2048 * 2);
    u16* qkv_b = scr;
    u16* ffh_b = scr;
    u16* qca_b = scr;
    u16* kvca_b = scr + (size_t)NR * 256;
    (void)in_sizes; (void)n_in;

    if (off > ws_size) {
        k_fillf<<<(out_size + 255) / 256, 256, 0, stream>>>((float*)d_out, out_size, 1000.0f);
        return;
    }

    k_conv_all<<<2048, 256, 0, stream>>>(enc_qkv_w, enc_out_w, enc_ff1_w, enc_ff2_w,
                                         dec_sa_qkv_w, dec_sa_out_w, dec_ca_qkv_w, dec_ca_out_w,
                                         dec_ff1_w, dec_ff2_w, w_eqkv);
    k_wsa<<<1024, 256, 0, stream>>>(dec_sa_qkv_w, dec_sa_qkv_b, dec_sa_out_w, dec_sa_out_b, wsa, bsa);
    k_embed<<<1024, 256, 0, stream>>>(x, codebook, pos, mask, h_f, h_b, addv, addvz);

    // ---- encoder ----
    for (int l = 0; l < 4; l++) {
        const u16* inb = l ? ctx_b : h_b;
        const float* inf = l ? ctx_f : h_f;
        k_gemm<64,64,false,true><<<768, 256, 0, stream>>>(inb, w_eqkv + (size_t)l*196608,
            enc_qkv_b + l*768, nullptr, qkv_b, 768, 256);
        k_attn<<<512, 256, 0, stream>>>(qkv_b, 768, qkv_b, 768, 256, 512, addv, attno);
        k_gemm<64,64,false,false><<<256, 256, 0, stream>>>(attno, w_eout + (size_t)l*65536,
            enc_out_b + l*256, gem_f, nullptr, 256, 256);
        k_ln<<<1024, 256, 0, stream>>>(inf, gem_f, enc_ln1_g + l*256, enc_ln1_b + l*256, ctx_f, ctx_b);
        k_gemm<128,128,true,true><<<512, 256, 0, stream>>>(ctx_b, w_eff1 + (size_t)l*524288,
            enc_ff1_b + l*2048, nullptr, ffh_b, 2048, 256);
        k_gemm_sk4<<<1024, 256, 0, stream>>>(ffh_b, w_eff2 + (size_t)l*524288,
            enc_ff2_b + l*256, gem_p);
        k_ln4<<<1024, 256, 0, stream>>>(ctx_f, gem_p, enc_ln2_g + l*256, enc_ln2_b + l*256, ctx_f, ctx_b);
    }

    // ---- decoder ----
    for (int l = 0; l < 4; l++) {
        const u16* inb = l ? dd_b : h_b;
        const float* inf = l ? dd_f : h_f;
        // self-attn == single GEMM with combined weight (out_w @ v_w)
        k_gemm<64,64,false,false><<<256, 256, 0, stream>>>(inb, wsa + (size_t)l*65536,
            bsa + l*256, gem_f, nullptr, 256, 256);
        k_ln<<<1024, 256, 0, stream>>>(inf, gem_f, dec_ln1_g + l*256, dec_ln1_b + l*256, dd_f, dd_b);
        // cross-attn: q-proj + kv-proj merged into one dispatch
        k_gemm2<<<768, 256, 0, stream>>>(dd_b, w_dcaq + (size_t)l*196608, dec_ca_qkv_b + l*768, qca_b,
                                         ctx_b, w_dcaq + (size_t)l*196608 + 65536,
                                         dec_ca_qkv_b + l*768 + 256, kvca_b);
        k_attn<<<512, 256, 0, stream>>>(qca_b, 256, kvca_b, 512, 0, 256, addvz, attno);
        k_gemm<64,64,false,false><<<256, 256, 0, stream>>>(attno, w_dcao + (size_t)l*65536,
            dec_ca_out_b + l*256, gem_f, nullptr, 256, 256);
        k_ln<<<1024, 256, 0, stream>>>(dd_f, gem_f, dec_ln2_g + l*256, dec_ln2_b + l*256, dd_f, dd_b);
        // FFN
        k_gemm<128,128,true,true><<<512, 256, 0, stream>>>(dd_b, w_dff1 + (size_t)l*524288,
            dec_ff1_b + l*2048, nullptr, ffh_b, 2048, 256);
        k_gemm_sk4<<<1024, 256, 0, stream>>>(ffh_b, w_dff2 + (size_t)l*524288,
            dec_ff2_b + l*256, gem_p);
        k_ln4<<<1024, 256, 0, stream>>>(dd_f, gem_p, dec_ln3_g + l*256, dec_ln3_b + l*256,
                                        (l == 3) ? (float*)d_out : dd_f, dd_b);
    }
}

// Round 14
// 579.568 us; speedup vs baseline: 1.9137x; 1.0376x over previous
//
#include <hip/hip_runtime.h>

typedef unsigned short u16;
typedef unsigned int   u32;
typedef short short8 __attribute__((ext_vector_type(8)));
typedef float f32x4  __attribute__((ext_vector_type(4)));

#define DEV static __device__ __forceinline__

static constexpr int S_ = 1024;   // seq len
static constexpr int D_ = 256;    // model dim
static constexpr int NR = 4096;   // B*S rows

DEV u16 f2bf(float x) {
    u32 u = __float_as_uint(x);
    return (u16)((u + 0x7FFFu + ((u >> 16) & 1u)) >> 16);
}
DEV float bf2f(u16 s) { return __uint_as_float(((u32)s) << 16); }

// ---------------- elementwise / prep kernels ----------------

__global__ __launch_bounds__(256) void k_fillf(float* __restrict__ o, int n, float v) {
    int i = blockIdx.x * 256 + threadIdx.x;
    if (i < n) o[i] = v;
}

__global__ __launch_bounds__(256) void k_conv_all(
        const float* __restrict__ s0, const float* __restrict__ s1, const float* __restrict__ s2,
        const float* __restrict__ s3, const float* __restrict__ s4, const float* __restrict__ s5,
        const float* __restrict__ s6, const float* __restrict__ s7, const float* __restrict__ s8,
        const float* __restrict__ s9, u16* __restrict__ dst) {
    constexpr int c0 = 786432/4,            c1 = c0 + 262144/4,  c2 = c1 + 2097152/4,
                  c3 = c2 + 2097152/4,      c4 = c3 + 786432/4,  c5 = c4 + 262144/4,
                  c6 = c5 + 786432/4,       c7 = c6 + 262144/4,  c8 = c7 + 2097152/4,
                  c9 = c8 + 2097152/4;
    for (int i = blockIdx.x * 256 + threadIdx.x; i < c9; i += gridDim.x * 256) {
        const float* src; int base;
        if      (i < c0) { src = s0; base = 0;  }
        else if (i < c1) { src = s1; base = c0; }
        else if (i < c2) { src = s2; base = c1; }
        else if (i < c3) { src = s3; base = c2; }
        else if (i < c4) { src = s4; base = c3; }
        else if (i < c5) { src = s5; base = c4; }
        else if (i < c6) { src = s6; base = c5; }
        else if (i < c7) { src = s7; base = c6; }
        else if (i < c8) { src = s8; base = c7; }
        else             { src = s9; base = c8; }
        float4 v = ((const float4*)src)[i - base];
        ushort4 o; o.x = f2bf(v.x); o.y = f2bf(v.y); o.z = f2bf(v.z); o.w = f2bf(v.w);
        ((ushort4*)dst)[i] = o;
    }
}

// combined dec self-attn weights: W_sa[l] = out_w[l] @ wv[l], b_sa[l] = out_w[l] @ bv[l] + out_b[l]
__global__ __launch_bounds__(256) void k_wsa(const float* __restrict__ qkvw, const float* __restrict__ qkvb,
                                             const float* __restrict__ outw, const float* __restrict__ outb,
                                             u16* __restrict__ wsa, float* __restrict__ bsa) {
    int l = blockIdx.x >> 8, n = blockIdx.x & 255, t = threadIdx.x;
    const float* wv = qkvw + (size_t)l * 196608 + 131072;
    const float* bv = qkvb + l * 768 + 512;
    const float* wo = outw + (size_t)l * 65536 + n * 256;
    float acc = 0.0f, pb = 0.0f;
    for (int j = 0; j < 256; j++) {
        float woj = wo[j];
        acc = fmaf(woj, wv[j * 256 + t], acc);
        pb  = fmaf(woj, bv[j], pb);
    }
    wsa[(size_t)l * 65536 + n * 256 + t] = f2bf(acc);
    if (t == 0) bsa[l * 256 + n] = pb + outb[l * 256 + n];
}

// embed + mask->addend fused
__global__ __launch_bounds__(256) void k_embed(const int* __restrict__ xx,
                                               const float* __restrict__ cb,
                                               const float* __restrict__ pos,
                                               const unsigned char* __restrict__ mask,
                                               float* __restrict__ hf, u16* __restrict__ hb,
                                               float* __restrict__ av, float* __restrict__ avz) {
    int wid = threadIdx.x >> 6, lane = threadIdx.x & 63;
    int row = blockIdx.x * 4 + wid;
    int sp = row & (S_ - 1);
    int tok = xx[row];
    float4 c = ((const float4*)(cb + (size_t)tok * D_))[lane];
    float4 p = ((const float4*)(pos + (size_t)sp * D_))[lane];
    float4 s; s.x = c.x + p.x; s.y = c.y + p.y; s.z = c.z + p.z; s.w = c.w + p.w;
    ((float4*)(hf + (size_t)row * D_))[lane] = s;
    ushort4 o; o.x = f2bf(s.x); o.y = f2bf(s.y); o.z = f2bf(s.z); o.w = f2bf(s.w);
    ((ushort4*)(hb + (size_t)row * D_))[lane] = o;
    if (lane == 0) { av[row] = mask[row] ? -2.0e9f : 0.0f; avz[row] = 0.0f; }
}

// residual + sum-4-bf16-partials + layernorm (after split-K ff2)
__global__ __launch_bounds__(256) void k_ln4(const float* __restrict__ x, const u16* __restrict__ yp,
                                             const float* __restrict__ gg, const float* __restrict__ bb,
                                             float* __restrict__ of, u16* __restrict__ ob) {
    int wid = threadIdx.x >> 6, lane = threadIdx.x & 63;
    int row = blockIdx.x * 4 + wid;
    float4 xv = ((const float4*)(x + (size_t)row * D_))[lane];
    float4 s = xv;
    #pragma unroll
    for (int kz = 0; kz < 4; kz++) {
        ushort4 yv = ((const ushort4*)(yp + (size_t)kz * NR * D_ + (size_t)row * D_))[lane];
        s.x += bf2f(yv.x); s.y += bf2f(yv.y); s.z += bf2f(yv.z); s.w += bf2f(yv.w);
    }
    float sum = s.x + s.y + s.z + s.w;
    float sq  = s.x * s.x + s.y * s.y + s.z * s.z + s.w * s.w;
    #pragma unroll
    for (int m = 1; m < 64; m <<= 1) { sum += __shfl_xor(sum, m, 64); sq += __shfl_xor(sq, m, 64); }
    float mean = sum * (1.0f / 256.0f);
    float var  = sq * (1.0f / 256.0f) - mean * mean;
    float rs = rsqrtf(var + 1e-5f);
    float4 gv = ((const float4*)gg)[lane];
    float4 bv = ((const float4*)bb)[lane];
    float4 o;
    o.x = (s.x - mean) * rs * gv.x + bv.x;
    o.y = (s.y - mean) * rs * gv.y + bv.y;
    o.z = (s.z - mean) * rs * gv.z + bv.z;
    o.w = (s.w - mean) * rs * gv.w + bv.w;
    ((float4*)(of + (size_t)row * D_))[lane] = o;
    ushort4 ub; ub.x = f2bf(o.x); ub.y = f2bf(o.y); ub.z = f2bf(o.z); ub.w = f2bf(o.w);
    ((ushort4*)(ob + (size_t)row * D_))[lane] = ub;
}

// ---------------- MFMA GEMM (round-5 structure):  C = A @ W^T + bias ----------------

template <int BM, int BN, bool RELU, bool OBF16>
__global__ __launch_bounds__(256) void k_gemm(const u16* __restrict__ A, const u16* __restrict__ Bw,
                                              const float* __restrict__ bias,
                                              float* __restrict__ Cf, u16* __restrict__ Cb,
                                              int Nn, int Kk) {
    constexpr int FM = BM / 32, FN = BN / 32;
    constexpr int LDA = 72;
    __shared__ __align__(16) u16 As[BM * LDA];
    __shared__ __align__(16) u16 Bs[BN * LDA];
    int tid = threadIdx.x, w = tid >> 6, lane = tid & 63;
    int lr = lane & 15, g = lane >> 4;
    int wm = w >> 1, wn = w & 1;
    int nbn = Nn / BN;
    int bid = blockIdx.x, nwg = gridDim.x;
    if ((nwg & 7) == 0) bid = (bid & 7) * (nwg >> 3) + (bid >> 3);
    int m0 = (bid / nbn) * BM, n0 = (bid % nbn) * BN;
    int trow = tid >> 3, tcol = (tid & 7) << 3;

    f32x4 acc[FM][FN] = {};

    for (int kb = 0; kb < Kk; kb += 64) {
        if (kb) __syncthreads();
        #pragma unroll
        for (int r = 0; r < BM / 32; r++) {
            int row = r * 32 + trow;
            uint4 v = *(const uint4*)(A + (size_t)(m0 + row) * Kk + kb + tcol);
            *(uint4*)(As + row * LDA + tcol) = v;
        }
        #pragma unroll
        for (int r = 0; r < BN / 32; r++) {
            int row = r * 32 + trow;
            uint4 v = *(const uint4*)(Bw + (size_t)(n0 + row) * Kk + kb + tcol);
            *(uint4*)(Bs + row * LDA + tcol) = v;
        }
        __syncthreads();
        #pragma unroll
        for (int kk = 0; kk < 2; kk++) {
            short8 af[FM], bfr[FN];
            #pragma unroll
            for (int mi = 0; mi < FM; mi++)
                af[mi] = *(const short8*)(As + (wm * (BM / 2) + mi * 16 + lr) * LDA + kk * 32 + g * 8);
            #pragma unroll
            for (int ni = 0; ni < FN; ni++)
                bfr[ni] = *(const short8*)(Bs + (wn * (BN / 2) + ni * 16 + lr) * LDA + kk * 32 + g * 8);
            #pragma unroll
            for (int mi = 0; mi < FM; mi++)
                #pragma unroll
                for (int ni = 0; ni < FN; ni++)
                    acc[mi][ni] = __builtin_amdgcn_mfma_f32_16x16x32_bf16(af[mi], bfr[ni], acc[mi][ni], 0, 0, 0);
        }
    }

    #pragma unroll
    for (int ni = 0; ni < FN; ni++) {
        int col = n0 + wn * (BN / 2) + ni * 16 + lr;
        float bi = bias[col];
        #pragma unroll
        for (int mi = 0; mi < FM; mi++) {
            #pragma unroll
            for (int jj = 0; jj < 4; jj++) {
                int row = m0 + wm * (BM / 2) + mi * 16 + g * 4 + jj;
                float v = acc[mi][ni][jj] + bi;
                if (RELU) v = fmaxf(v, 0.0f);
                if (OBF16) Cb[(size_t)row * Nn + col] = f2bf(v);
                else       Cf[(size_t)row * Nn + col] = v;
            }
        }
    }
}

// fused GEMM (M=4096, N=256, K=256) + residual + LayerNorm.
// BM=16, BN=256 (full row in block -> LN in epilogue). grid 256, XCD-chunked.
// wave w owns cols 64w..64w+63 (FN=4). Cs aliases Bs after a barrier.
__global__ __launch_bounds__(256) void k_gemm_ln(const u16* __restrict__ A, const u16* __restrict__ Bw,
                                                 const float* __restrict__ bias,
                                                 const float* __restrict__ resid,
                                                 const float* __restrict__ gg, const float* __restrict__ bb,
                                                 float* __restrict__ of, u16* __restrict__ ob) {
    constexpr int LDA = 72, Kk = 256;
    __shared__ __align__(16) u16 As[16 * LDA];
    __shared__ __align__(16) u16 Bs[256 * LDA];     // 36 KB; f32 Cs[16][260] aliases (16.6 KB)
    int tid = threadIdx.x, w = tid >> 6, lane = tid & 63;
    int lr = lane & 15, g = lane >> 4;
    int bid = blockIdx.x;
    bid = (bid & 7) * 32 + (bid >> 3);              // XCD-chunked over 256
    int m0 = bid * 16;
    int trow = tid >> 3, tcol = (tid & 7) << 3;     // B staging: 32 rows/pass

    f32x4 acc[4] = {};

    for (int kb = 0; kb < Kk; kb += 64) {
        if (kb) __syncthreads();
        if (tid < 128) {                            // A tile: 16 rows x 64 = 128 uint4
            int row = tid >> 3;
            uint4 v = *(const uint4*)(A + (size_t)(m0 + row) * Kk + kb + tcol);
            *(uint4*)(As + row * LDA + tcol) = v;
        }
        #pragma unroll
        for (int r = 0; r < 8; r++) {               // B tile: 256 rows x 64
            int row = r * 32 + trow;
            uint4 v = *(const uint4*)(Bw + (size_t)row * Kk + kb + tcol);
            *(uint4*)(Bs + row * LDA + tcol) = v;
        }
        __syncthreads();
        #pragma unroll
        for (int kk = 0; kk < 2; kk++) {
            short8 af = *(const short8*)(As + lr * LDA + kk * 32 + g * 8);
            #pragma unroll
            for (int ni = 0; ni < 4; ni++) {
                short8 bfr = *(const short8*)(Bs + (w * 64 + ni * 16 + lr) * LDA + kk * 32 + g * 8);
                acc[ni] = __builtin_amdgcn_mfma_f32_16x16x32_bf16(af, bfr, acc[ni], 0, 0, 0);
            }
        }
    }

    __syncthreads();                                // all MFMA reads of Bs done
    float* Cs = (float*)Bs;                         // [16][260]
    #pragma unroll
    for (int ni = 0; ni < 4; ni++) {
        int col = w * 64 + ni * 16 + lr;
        float bi = bias[col];
        #pragma unroll
        for (int jj = 0; jj < 4; jj++)
            Cs[(g * 4 + jj) * 260 + col] = acc[ni][jj] + bi;
    }
    __syncthreads();

    // LN: 16 threads per row; thread t handles row t>>4, cols (t&15)*16 .. +15
    int row = tid >> 4, c0 = (tid & 15) * 16;
    float v[16];
    float sum = 0.0f, sq = 0.0f;
    #pragma unroll
    for (int i = 0; i < 4; i++) {
        float4 cv = *(float4*)(Cs + row * 260 + c0 + i * 4);
        float4 rv = *(const float4*)(resid + (size_t)(m0 + row) * D_ + c0 + i * 4);
        v[4*i]   = cv.x + rv.x; v[4*i+1] = cv.y + rv.y;
        v[4*i+2] = cv.z + rv.z; v[4*i+3] = cv.w + rv.w;
    }
    #pragma unroll
    for (int i = 0; i < 16; i++) { sum += v[i]; sq += v[i] * v[i]; }
    #pragma unroll
    for (int m = 1; m < 16; m <<= 1) { sum += __shfl_xor(sum, m, 64); sq += __shfl_xor(sq, m, 64); }
    float mean = sum * (1.0f / 256.0f);
    float var  = sq * (1.0f / 256.0f) - mean * mean;
    float rs = rsqrtf(var + 1e-5f);
    float* op = of + (size_t)(m0 + row) * D_ + c0;
    u16*   bp = ob + (size_t)(m0 + row) * D_ + c0;
    #pragma unroll
    for (int i = 0; i < 4; i++) {
        float4 gv = *(const float4*)(gg + c0 + i * 4);
        float4 bv = *(const float4*)(bb + c0 + i * 4);
        float4 o;
        o.x = (v[4*i]   - mean) * rs * gv.x + bv.x;
        o.y = (v[4*i+1] - mean) * rs * gv.y + bv.y;
        o.z = (v[4*i+2] - mean) * rs * gv.z + bv.z;
        o.w = (v[4*i+3] - mean) * rs * gv.w + bv.w;
        *(float4*)(op + i * 4) = o;
        ushort4 ub; ub.x = f2bf(o.x); ub.y = f2bf(o.y); ub.z = f2bf(o.z); ub.w = f2bf(o.w);
        *(ushort4*)(bp + i * 4) = ub;
    }
}

// merged qca+kvca: grid 768 (XCD-chunked). Blocks 0..255: qca; 256..767: kvca.
__global__ __launch_bounds__(256) void k_gemm2(const u16* __restrict__ A0, const u16* __restrict__ W0,
                                               const float* __restrict__ b0, u16* __restrict__ C0,
                                               const u16* __restrict__ A1, const u16* __restrict__ W1,
                                               const float* __restrict__ b1, u16* __restrict__ C1) {
    constexpr int LDA = 72, Kk = 256;
    __shared__ __align__(16) u16 As[64 * LDA];
    __shared__ __align__(16) u16 Bs[64 * LDA];
    int tid = threadIdx.x, w = tid >> 6, lane = tid & 63;
    int lr = lane & 15, g = lane >> 4;
    int wm = w >> 1, wn = w & 1;
    int bid = blockIdx.x;
    bid = (bid & 7) * 96 + (bid >> 3);
    const u16 *A, *Bw; const float* bias; u16* Cb; int Nn, nbn, seg;
    if (bid < 256) { A = A0; Bw = W0; bias = b0; Cb = C0; Nn = 256; nbn = 4; seg = bid; }
    else           { A = A1; Bw = W1; bias = b1; Cb = C1; Nn = 512; nbn = 8; seg = bid - 256; }
    int m0 = (seg / nbn) * 64, n0 = (seg % nbn) * 64;
    int trow = tid >> 3, tcol = (tid & 7) << 3;

    f32x4 acc[2][2] = {};

    for (int kb = 0; kb < Kk; kb += 64) {
        if (kb) __syncthreads();
        #pragma unroll
        for (int r = 0; r < 2; r++) {
            int row = r * 32 + trow;
            uint4 va = *(const uint4*)(A + (size_t)(m0 + row) * Kk + kb + tcol);
            *(uint4*)(As + row * LDA + tcol) = va;
            uint4 vb = *(const uint4*)(Bw + (size_t)(n0 + row) * Kk + kb + tcol);
            *(uint4*)(Bs + row * LDA + tcol) = vb;
        }
        __syncthreads();
        #pragma unroll
        for (int kk = 0; kk < 2; kk++) {
            short8 af[2], bfr[2];
            #pragma unroll
            for (int mi = 0; mi < 2; mi++)
                af[mi] = *(const short8*)(As + (wm * 32 + mi * 16 + lr) * LDA + kk * 32 + g * 8);
            #pragma unroll
            for (int ni = 0; ni < 2; ni++)
                bfr[ni] = *(const short8*)(Bs + (wn * 32 + ni * 16 + lr) * LDA + kk * 32 + g * 8);
            #pragma unroll
            for (int mi = 0; mi < 2; mi++)
                #pragma unroll
                for (int ni = 0; ni < 2; ni++)
                    acc[mi][ni] = __builtin_amdgcn_mfma_f32_16x16x32_bf16(af[mi], bfr[ni], acc[mi][ni], 0, 0, 0);
        }
    }

    #pragma unroll
    for (int ni = 0; ni < 2; ni++) {
        int col = n0 + wn * 32 + ni * 16 + lr;
        float bi = bias[col];
        #pragma unroll
        for (int mi = 0; mi < 2; mi++)
            #pragma unroll
            for (int jj = 0; jj < 4; jj++) {
                int row = m0 + wm * 32 + mi * 16 + g * 4 + jj;
                Cb[(size_t)row * Nn + col] = f2bf(acc[mi][ni][jj] + bi);
            }
    }
}

// ff2 split-K=4: grid 1024; bf16 partials, bias folded into kz==0.
__global__ __launch_bounds__(256) void k_gemm_sk4(const u16* __restrict__ A, const u16* __restrict__ Bw,
                                                  const float* __restrict__ bias, u16* __restrict__ Cp) {
    constexpr int LDA = 72, Nn = 256, Kk = 2048;
    __shared__ __align__(16) u16 As[64 * LDA];
    __shared__ __align__(16) u16 Bs[64 * LDA];
    int tid = threadIdx.x, w = tid >> 6, lane = tid & 63;
    int lr = lane & 15, g = lane >> 4;
    int wm = w >> 1, wn = w & 1;
    int kz = blockIdx.x >> 8;
    int mn = blockIdx.x & 255;
    mn = (mn & 7) * 32 + (mn >> 3);
    int m0 = (mn >> 2) * 64, n0 = (mn & 3) * 64;
    int kbeg = kz * 512;
    int trow = tid >> 3, tcol = (tid & 7) << 3;

    f32x4 acc[2][2] = {};

    for (int kb = kbeg; kb < kbeg + 512; kb += 64) {
        if (kb != kbeg) __syncthreads();
        #pragma unroll
        for (int r = 0; r < 2; r++) {
            int row = r * 32 + trow;
            uint4 va = *(const uint4*)(A + (size_t)(m0 + row) * Kk + kb + tcol);
            *(uint4*)(As + row * LDA + tcol) = va;
            uint4 vb = *(const uint4*)(Bw + (size_t)(n0 + row) * Kk + kb + tcol);
            *(uint4*)(Bs + row * LDA + tcol) = vb;
        }
        __syncthreads();
        #pragma unroll
        for (int kk = 0; kk < 2; kk++) {
            short8 af[2], bfr[2];
            #pragma unroll
            for (int mi = 0; mi < 2; mi++)
                af[mi] = *(const short8*)(As + (wm * 32 + mi * 16 + lr) * LDA + kk * 32 + g * 8);
            #pragma unroll
            for (int ni = 0; ni < 2; ni++)
                bfr[ni] = *(const short8*)(Bs + (wn * 32 + ni * 16 + lr) * LDA + kk * 32 + g * 8);
            #pragma unroll
            for (int mi = 0; mi < 2; mi++)
                #pragma unroll
                for (int ni = 0; ni < 2; ni++)
                    acc[mi][ni] = __builtin_amdgcn_mfma_f32_16x16x32_bf16(af[mi], bfr[ni], acc[mi][ni], 0, 0, 0);
        }
    }

    u16* Cz = Cp + (size_t)kz * NR * Nn;
    #pragma unroll
    for (int ni = 0; ni < 2; ni++) {
        int col = n0 + wn * 32 + ni * 16 + lr;
        float bi = (kz == 0) ? bias[col] : 0.0f;
        #pragma unroll
        for (int mi = 0; mi < 2; mi++)
            #pragma unroll
            for (int jj = 0; jj < 4; jj++) {
                int row = m0 + wm * 32 + mi * 16 + g * 4 + jj;
                Cz[(size_t)row * Nn + col] = f2bf(acc[mi][ni][jj] + bi);
            }
    }
}

// ---------------- MFMA flash attention (HD=32), exp2-domain softmax, K/V dbuf ----------------

__global__ __launch_bounds__(256) void k_attn(const u16* __restrict__ qp, int qs,
                                              const u16* __restrict__ kvp, int ks, int koff, int voff,
                                              const float* __restrict__ addv, u16* __restrict__ out) {
    __shared__ __align__(16) u16 Kl[2][128 * 32];
    __shared__ __align__(16) u16 VTl[2][32 * 136];
    __shared__ __align__(16) u16 Pl[4 * 16 * 136];
    __shared__ float Al[2][128];

    int tid = threadIdx.x, w = tid >> 6, lane = tid & 63;
    int lr = lane & 15, g = lane >> 4;
    int blk = blockIdx.x;
    blk = (blk & 7) * 64 + (blk >> 3);
    int qb = blk & 15, h = (blk >> 4) & 7, b = blk >> 7;
    int q0 = qb * 64 + w * 16;
    const float QS2 = 0.17677669529663687f * 1.4426950408889634f;

    short8 qf = *(const short8*)(qp + (size_t)(b * S_ + q0 + lr) * qs + h * 32 + g * 8);

    f32x4 o0 = {0.f, 0.f, 0.f, 0.f}, o1 = {0.f, 0.f, 0.f, 0.f};
    float m_run = -3.0e38f, l_run = 0.0f;
    float sreg[8][4];
    u16* Pw = Pl + w * 16 * 136;

    int key_t = tid >> 1, dh = (tid & 1) * 16;
    const u16* kbase = kvp + (size_t)(b * S_) * ks;

    uint4 ka0, ka1;
    union { uint4 v[2]; u16 s[16]; } vu;
    float alv = 0.0f;
    auto ldregs = [&](int kb) {
        const u16* srck = kbase + (size_t)(kb * 128 + key_t) * ks + koff + h * 32 + dh;
        ka0 = *(const uint4*)srck;
        ka1 = *(const uint4*)(srck + 8);
        const u16* srcv = kbase + (size_t)(kb * 128 + key_t) * ks + voff + h * 32 + dh;
        vu.v[0] = *(const uint4*)srcv;
        vu.v[1] = *(const uint4*)(srcv + 8);
        if (tid < 128) alv = addv[b * S_ + kb * 128 + tid];
    };
    auto stbuf = [&](int buf) {
        *(uint4*)(&Kl[buf][key_t * 32 + dh])     = ka0;
        *(uint4*)(&Kl[buf][key_t * 32 + dh + 8]) = ka1;
        #pragma unroll
        for (int i = 0; i < 16; i++) VTl[buf][(dh + i) * 136 + key_t] = vu.s[i];
        if (tid < 128) Al[buf][tid] = alv;
    };

    ldregs(0); stbuf(0);
    int cur = 0;
    for (int kb = 0; kb < 8; kb++) {
        __syncthreads();

        #pragma unroll
        for (int t = 0; t < 8; t++) {
            short8 kf = *(const short8*)(&Kl[cur][(t * 16 + lr) * 32 + g * 8]);
            f32x4 z = {0.f, 0.f, 0.f, 0.f};
            f32x4 st = __builtin_amdgcn_mfma_f32_16x16x32_bf16(kf, qf, z, 0, 0, 0);
            #pragma unroll
            for (int jj = 0; jj < 4; jj++) sreg[t][jj] = st[jj] * QS2 + Al[cur][t * 16 + g * 4 + jj];
        }

        if (kb < 7) ldregs(kb + 1);

        float mb = -3.0e38f;
        #pragma unroll
        for (int t = 0; t < 8; t++)
            #pragma unroll
            for (int jj = 0; jj < 4; jj++) mb = fmaxf(mb, sreg[t][jj]);
        mb = fmaxf(mb, __shfl_xor(mb, 16, 64));
        mb = fmaxf(mb, __shfl_xor(mb, 32, 64));
        float mnew = fmaxf(m_run, mb);
        float sc = __builtin_amdgcn_exp2f(m_run - mnew);
        float ls = 0.f;
        #pragma unroll
        for (int t = 0; t < 8; t++)
            #pragma unroll
            for (int jj = 0; jj < 4; jj++) {
                float p = __builtin_amdgcn_exp2f(sreg[t][jj] - mnew);
                sreg[t][jj] = p; ls += p;
            }
        ls += __shfl_xor(ls, 16, 64); ls += __shfl_xor(ls, 32, 64);
        l_run = l_run * sc + ls; m_run = mnew;
        #pragma unroll
        for (int jj = 0; jj < 4; jj++) {
            float scj = __shfl(sc, 20 * g + jj, 64);
            o0[jj] *= scj; o1[jj] *= scj;
        }

        #pragma unroll
        for (int t = 0; t < 8; t++) {
            u32 u0 = (u32)f2bf(sreg[t][0]) | ((u32)f2bf(sreg[t][1]) << 16);
            u32 u1 = (u32)f2bf(sreg[t][2]) | ((u32)f2bf(sreg[t][3]) << 16);
            *(uint2*)(Pw + lr * 136 + t * 16 + g * 4) = make_uint2(u0, u1);
        }

        #pragma unroll
        for (int c = 0; c < 4; c++) {
            short8 pa = *(const short8*)(Pw + lr * 136 + c * 32 + g * 8);
            short8 v0 = *(const short8*)(&VTl[cur][lr * 136 + c * 32 + g * 8]);
            short8 v1 = *(const short8*)(&VTl[cur][(16 + lr) * 136 + c * 32 + g * 8]);
            o0 = __builtin_amdgcn_mfma_f32_16x16x32_bf16(pa, v0, o0, 0, 0, 0);
            o1 = __builtin_amdgcn_mfma_f32_16x16x32_bf16(pa, v1, o1, 0, 0, 0);
        }

        __syncthreads();
        if (kb < 7) stbuf(cur ^ 1);
        cur ^= 1;
    }

    float li = 1.0f / l_run;
    #pragma unroll
    for (int jj = 0; jj < 4; jj++) {
        float lij = __shfl(li, 20 * g + jj, 64);
        int r = q0 + g * 4 + jj;
        u16* op = out + (size_t)(b * S_ + r) * 256 + h * 32;
        op[lr]      = f2bf(o0[jj] * lij);
        op[16 + lr] = f2bf(o1[jj] * lij);
    }
}

// ---------------- host orchestration ----------------

extern "C" void kernel_launch(void* const* d_in, const int* in_sizes, int n_in,
                              void* d_out, int out_size, void* d_ws, size_t ws_size,
                              hipStream_t stream) {
    const int* x                = (const int*)d_in[0];
    const unsigned char* mask   = (const unsigned char*)d_in[1];
    const float* codebook       = (const float*)d_in[2];
    const float* pos            = (const float*)d_in[3];
    const float* enc_qkv_w = (const float*)d_in[4];  const float* enc_qkv_b = (const float*)d_in[5];
    const float* enc_out_w = (const float*)d_in[6];  const float* enc_out_b = (const float*)d_in[7];
    const float* enc_ff1_w = (const float*)d_in[8];  const float* enc_ff1_b = (const float*)d_in[9];
    const float* enc_ff2_w = (const float*)d_in[10]; const float* enc_ff2_b = (const float*)d_in[11];
    const float* enc_ln1_g = (const float*)d_in[12]; const float* enc_ln1_b = (const float*)d_in[13];
    const float* enc_ln2_g = (const float*)d_in[14]; const float* enc_ln2_b = (const float*)d_in[15];
    const float* dec_sa_qkv_w = (const float*)d_in[16]; const float* dec_sa_qkv_b = (const float*)d_in[17];
    const float* dec_sa_out_w = (const float*)d_in[18]; const float* dec_sa_out_b = (const float*)d_in[19];
    const float* dec_ca_qkv_w = (const float*)d_in[20]; const float* dec_ca_qkv_b = (const float*)d_in[21];
    const float* dec_ca_out_w = (const float*)d_in[22]; const float* dec_ca_out_b = (const float*)d_in[23];
    const float* dec_ff1_w = (const float*)d_in[24]; const float* dec_ff1_b = (const float*)d_in[25];
    const float* dec_ff2_w = (const float*)d_in[26]; const float* dec_ff2_b = (const float*)d_in[27];
    const float* dec_ln1_g = (const float*)d_in[28]; const float* dec_ln1_b = (const float*)d_in[29];
    const float* dec_ln2_g = (const float*)d_in[30]; const float* dec_ln2_b = (const float*)d_in[31];
    const float* dec_ln3_g = (const float*)d_in[32]; const float* dec_ln3_b = (const float*)d_in[33];

    char* ws = (char*)d_ws; size_t off = 0;
    auto alloc = [&](size_t b) { char* p = ws + off; off += (b + 255) & ~(size_t)255; return p; };

    u16* w_eqkv  = (u16*)alloc((size_t)786432 * 2);
    u16* w_eout  = (u16*)alloc((size_t)262144 * 2);
    u16* w_eff1  = (u16*)alloc((size_t)2097152 * 2);
    u16* w_eff2  = (u16*)alloc((size_t)2097152 * 2);
    u16* w_dsaq  = (u16*)alloc((size_t)786432 * 2);
    u16* w_dsao  = (u16*)alloc((size_t)262144 * 2);
    u16* w_dcaq  = (u16*)alloc((size_t)786432 * 2);
    u16* w_dcao  = (u16*)alloc((size_t)262144 * 2);
    u16* w_dff1  = (u16*)alloc((size_t)2097152 * 2);
    u16* w_dff2  = (u16*)alloc((size_t)2097152 * 2);
    u16*   wsa   = (u16*)  alloc((size_t)4 * 65536 * 2);
    float* bsa   = (float*)alloc((size_t)4 * 256 * 4);
    float* h_f   = (float*)alloc((size_t)NR * D_ * 4);
    u16*   h_b   = (u16*)  alloc((size_t)NR * D_ * 2);
    float* ctx_f = (float*)alloc((size_t)NR * D_ * 4);
    u16*   ctx_b = (u16*)  alloc((size_t)NR * D_ * 2);
    float* dd_f  = (float*)alloc((size_t)NR * D_ * 4);
    u16*   dd_b  = (u16*)  alloc((size_t)NR * D_ * 2);
    u16*   gem_p = (u16*)  alloc((size_t)4 * NR * 256 * 2);
    u16*   attno = (u16*)  alloc((size_t)NR * 256 * 2);
    float* addv  = (float*)alloc((size_t)NR * 4);
    float* addvz = (float*)alloc((size_t)NR * 4);
    u16* scr = (u16*)alloc((size_t)NR * 2048 * 2);
    u16* qkv_b = scr;
    u16* ffh_b = scr;
    u16* qca_b = scr;
    u16* kvca_b = scr + (size_t)NR * 256;
    (void)in_sizes; (void)n_in;

    if (off > ws_size) {
        k_fillf<<<(out_size + 255) / 256, 256, 0, stream>>>((float*)d_out, out_size, 1000.0f);
        return;
    }

    k_conv_all<<<2048, 256, 0, stream>>>(enc_qkv_w, enc_out_w, enc_ff1_w, enc_ff2_w,
                                         dec_sa_qkv_w, dec_sa_out_w, dec_ca_qkv_w, dec_ca_out_w,
                                         dec_ff1_w, dec_ff2_w, w_eqkv);
    k_wsa<<<1024, 256, 0, stream>>>(dec_sa_qkv_w, dec_sa_qkv_b, dec_sa_out_w, dec_sa_out_b, wsa, bsa);
    k_embed<<<1024, 256, 0, stream>>>(x, codebook, pos, mask, h_f, h_b, addv, addvz);

    // ---- encoder ----
    for (int l = 0; l < 4; l++) {
        const u16* inb = l ? ctx_b : h_b;
        const float* inf = l ? ctx_f : h_f;
        k_gemm<64,64,false,true><<<768, 256, 0, stream>>>(inb, w_eqkv + (size_t)l*196608,
            enc_qkv_b + l*768, nullptr, qkv_b, 768, 256);
        k_attn<<<512, 256, 0, stream>>>(qkv_b, 768, qkv_b, 768, 256, 512, addv, attno);
        k_gemm_ln<<<256, 256, 0, stream>>>(attno, w_eout + (size_t)l*65536, enc_out_b + l*256,
            inf, enc_ln1_g + l*256, enc_ln1_b + l*256, ctx_f, ctx_b);
        k_gemm<128,128,true,true><<<512, 256, 0, stream>>>(ctx_b, w_eff1 + (size_t)l*524288,
            enc_ff1_b + l*2048, nullptr, ffh_b, 2048, 256);
        k_gemm_sk4<<<1024, 256, 0, stream>>>(ffh_b, w_eff2 + (size_t)l*524288,
            enc_ff2_b + l*256, gem_p);
        k_ln4<<<1024, 256, 0, stream>>>(ctx_f, gem_p, enc_ln2_g + l*256, enc_ln2_b + l*256, ctx_f, ctx_b);
    }

    // ---- decoder ----
    for (int l = 0; l < 4; l++) {
        const u16* inb = l ? dd_b : h_b;
        const float* inf = l ? dd_f : h_f;
        // self-attn (combined weight) + ln1 fused
        k_gemm_ln<<<256, 256, 0, stream>>>(inb, wsa + (size_t)l*65536, bsa + l*256,
            inf, dec_ln1_g + l*256, dec_ln1_b + l*256, dd_f, dd_b);
        // cross-attn: q-proj + kv-proj merged
        k_gemm2<<<768, 256, 0, stream>>>(dd_b, w_dcaq + (size_t)l*196608, dec_ca_qkv_b + l*768, qca_b,
                                         ctx_b, w_dcaq + (size_t)l*196608 + 65536,
                                         dec_ca_qkv_b + l*768 + 256, kvca_b);
        k_attn<<<512, 256, 0, stream>>>(qca_b, 256, kvca_b, 512, 0, 256, addvz, attno);
        // ca out-proj + ln2 fused
        k_gemm_ln<<<256, 256, 0, stream>>>(attno, w_dcao + (size_t)l*65536, dec_ca_out_b + l*256,
            dd_f, dec_ln2_g + l*256, dec_ln2_b + l*256, dd_f, dd_b);
        // FFN
        k_gemm<128,128,true,true><<<512, 256, 0, stream>>>(dd_b, w_dff1 + (size_t)l*524288,
            dec_ff1_b + l*2048, nullptr, ffh_b, 2048, 256);
        k_gemm_sk4<<<1024, 256, 0, stream>>>(ffh_b, w_dff2 + (size_t)l*524288,
            dec_ff2_b + l*256, gem_p);
        k_ln4<<<1024, 256, 0, stream>>>(dd_f, gem_p, dec_ln3_g + l*256, dec_ln3_b + l*256,
                                        (l == 3) ? (float*)d_out : dd_f, dd_b);
    }
}

// Round 15
// 575.792 us; speedup vs baseline: 1.9262x; 1.0066x over previous
//
#include <hip/hip_runtime.h>

typedef unsigned short u16;
typedef unsigned int   u32;
typedef short short8 __attribute__((ext_vector_type(8)));
typedef float f32x4  __attribute__((ext_vector_type(4)));

#define DEV static __device__ __forceinline__

static constexpr int S_ = 1024;   // seq len
static constexpr int D_ = 256;    // model dim
static constexpr int NR = 4096;   // B*S rows

DEV u16 f2bf(float x) {
    u32 u = __float_as_uint(x);
    return (u16)((u + 0x7FFFu + ((u >> 16) & 1u)) >> 16);
}
DEV float bf2f(u16 s) { return __uint_as_float(((u32)s) << 16); }

// ---------------- prep: weight conversion + combined SA weight + embed, ONE dispatch ----------------

__global__ __launch_bounds__(256) void k_fillf(float* __restrict__ o, int n, float v) {
    int i = blockIdx.x * 256 + threadIdx.x;
    if (i < n) o[i] = v;
}

// blocks 0..2047: f32->bf16 weight conv (grid-stride)
// blocks 2048..3071: W_sa = out_w @ wv, b_sa = out_w @ bv + out_b
// blocks 3072..4095: embed + mask->addend
__global__ __launch_bounds__(256) void k_prep(
        const float* __restrict__ s0, const float* __restrict__ s1, const float* __restrict__ s2,
        const float* __restrict__ s3, const float* __restrict__ s4, const float* __restrict__ s5,
        const float* __restrict__ s6, const float* __restrict__ s7, const float* __restrict__ s8,
        const float* __restrict__ s9, u16* __restrict__ dst,
        const float* __restrict__ saqw, const float* __restrict__ saqb,
        const float* __restrict__ saow, const float* __restrict__ saob,
        u16* __restrict__ wsa, float* __restrict__ bsa,
        const int* __restrict__ xx, const float* __restrict__ cb, const float* __restrict__ pos,
        const unsigned char* __restrict__ mask,
        float* __restrict__ hf, u16* __restrict__ hb,
        float* __restrict__ av, float* __restrict__ avz) {
    int bid = blockIdx.x, t = threadIdx.x;
    if (bid < 2048) {
        constexpr int c0 = 786432/4,            c1 = c0 + 262144/4,  c2 = c1 + 2097152/4,
                      c3 = c2 + 2097152/4,      c4 = c3 + 786432/4,  c5 = c4 + 262144/4,
                      c6 = c5 + 786432/4,       c7 = c6 + 262144/4,  c8 = c7 + 2097152/4,
                      c9 = c8 + 2097152/4;
        for (int i = bid * 256 + t; i < c9; i += 2048 * 256) {
            const float* src; int base;
            if      (i < c0) { src = s0; base = 0;  }
            else if (i < c1) { src = s1; base = c0; }
            else if (i < c2) { src = s2; base = c1; }
            else if (i < c3) { src = s3; base = c2; }
            else if (i < c4) { src = s4; base = c3; }
            else if (i < c5) { src = s5; base = c4; }
            else if (i < c6) { src = s6; base = c5; }
            else if (i < c7) { src = s7; base = c6; }
            else if (i < c8) { src = s8; base = c7; }
            else             { src = s9; base = c8; }
            float4 v = ((const float4*)src)[i - base];
            ushort4 o; o.x = f2bf(v.x); o.y = f2bf(v.y); o.z = f2bf(v.z); o.w = f2bf(v.w);
            ((ushort4*)dst)[i] = o;
        }
    } else if (bid < 3072) {
        int l = (bid - 2048) >> 8, n = (bid - 2048) & 255;
        const float* wv = saqw + (size_t)l * 196608 + 131072;
        const float* bv = saqb + l * 768 + 512;
        const float* wo = saow + (size_t)l * 65536 + n * 256;
        float acc = 0.0f, pb = 0.0f;
        for (int j = 0; j < 256; j++) {
            float woj = wo[j];
            acc = fmaf(woj, wv[j * 256 + t], acc);
            pb  = fmaf(woj, bv[j], pb);
        }
        wsa[(size_t)l * 65536 + n * 256 + t] = f2bf(acc);
        if (t == 0) bsa[l * 256 + n] = pb + saob[l * 256 + n];
    } else {
        int wid = t >> 6, lane = t & 63;
        int row = (bid - 3072) * 4 + wid;
        int sp = row & (S_ - 1);
        int tok = xx[row];
        float4 c = ((const float4*)(cb + (size_t)tok * D_))[lane];
        float4 p = ((const float4*)(pos + (size_t)sp * D_))[lane];
        float4 s; s.x = c.x + p.x; s.y = c.y + p.y; s.z = c.z + p.z; s.w = c.w + p.w;
        ((float4*)(hf + (size_t)row * D_))[lane] = s;
        ushort4 o; o.x = f2bf(s.x); o.y = f2bf(s.y); o.z = f2bf(s.z); o.w = f2bf(s.w);
        ((ushort4*)(hb + (size_t)row * D_))[lane] = o;
        if (lane == 0) { av[row] = mask[row] ? -2.0e9f : 0.0f; avz[row] = 0.0f; }
    }
}

// residual + sum-4-bf16-partials + layernorm (after split-K ff2)
__global__ __launch_bounds__(256) void k_ln4(const float* __restrict__ x, const u16* __restrict__ yp,
                                             const float* __restrict__ gg, const float* __restrict__ bb,
                                             float* __restrict__ of, u16* __restrict__ ob) {
    int wid = threadIdx.x >> 6, lane = threadIdx.x & 63;
    int row = blockIdx.x * 4 + wid;
    float4 xv = ((const float4*)(x + (size_t)row * D_))[lane];
    float4 s = xv;
    #pragma unroll
    for (int kz = 0; kz < 4; kz++) {
        ushort4 yv = ((const ushort4*)(yp + (size_t)kz * NR * D_ + (size_t)row * D_))[lane];
        s.x += bf2f(yv.x); s.y += bf2f(yv.y); s.z += bf2f(yv.z); s.w += bf2f(yv.w);
    }
    float sum = s.x + s.y + s.z + s.w;
    float sq  = s.x * s.x + s.y * s.y + s.z * s.z + s.w * s.w;
    #pragma unroll
    for (int m = 1; m < 64; m <<= 1) { sum += __shfl_xor(sum, m, 64); sq += __shfl_xor(sq, m, 64); }
    float mean = sum * (1.0f / 256.0f);
    float var  = sq * (1.0f / 256.0f) - mean * mean;
    float rs = rsqrtf(var + 1e-5f);
    float4 gv = ((const float4*)gg)[lane];
    float4 bv = ((const float4*)bb)[lane];
    float4 o;
    o.x = (s.x - mean) * rs * gv.x + bv.x;
    o.y = (s.y - mean) * rs * gv.y + bv.y;
    o.z = (s.z - mean) * rs * gv.z + bv.z;
    o.w = (s.w - mean) * rs * gv.w + bv.w;
    ((float4*)(of + (size_t)row * D_))[lane] = o;
    ushort4 ub; ub.x = f2bf(o.x); ub.y = f2bf(o.y); ub.z = f2bf(o.z); ub.w = f2bf(o.w);
    ((ushort4*)(ob + (size_t)row * D_))[lane] = ub;
}

// ---------------- MFMA GEMM (round-5 structure):  C = A @ W^T + bias ----------------

template <int BM, int BN, bool RELU, bool OBF16>
__global__ __launch_bounds__(256) void k_gemm(const u16* __restrict__ A, const u16* __restrict__ Bw,
                                              const float* __restrict__ bias,
                                              float* __restrict__ Cf, u16* __restrict__ Cb,
                                              int Nn, int Kk) {
    constexpr int FM = BM / 32, FN = BN / 32;
    constexpr int LDA = 72;
    __shared__ __align__(16) u16 As[BM * LDA];
    __shared__ __align__(16) u16 Bs[BN * LDA];
    int tid = threadIdx.x, w = tid >> 6, lane = tid & 63;
    int lr = lane & 15, g = lane >> 4;
    int wm = w >> 1, wn = w & 1;
    int nbn = Nn / BN;
    int bid = blockIdx.x, nwg = gridDim.x;
    if ((nwg & 7) == 0) bid = (bid & 7) * (nwg >> 3) + (bid >> 3);
    int m0 = (bid / nbn) * BM, n0 = (bid % nbn) * BN;
    int trow = tid >> 3, tcol = (tid & 7) << 3;

    f32x4 acc[FM][FN] = {};

    for (int kb = 0; kb < Kk; kb += 64) {
        if (kb) __syncthreads();
        #pragma unroll
        for (int r = 0; r < BM / 32; r++) {
            int row = r * 32 + trow;
            uint4 v = *(const uint4*)(A + (size_t)(m0 + row) * Kk + kb + tcol);
            *(uint4*)(As + row * LDA + tcol) = v;
        }
        #pragma unroll
        for (int r = 0; r < BN / 32; r++) {
            int row = r * 32 + trow;
            uint4 v = *(const uint4*)(Bw + (size_t)(n0 + row) * Kk + kb + tcol);
            *(uint4*)(Bs + row * LDA + tcol) = v;
        }
        __syncthreads();
        #pragma unroll
        for (int kk = 0; kk < 2; kk++) {
            short8 af[FM], bfr[FN];
            #pragma unroll
            for (int mi = 0; mi < FM; mi++)
                af[mi] = *(const short8*)(As + (wm * (BM / 2) + mi * 16 + lr) * LDA + kk * 32 + g * 8);
            #pragma unroll
            for (int ni = 0; ni < FN; ni++)
                bfr[ni] = *(const short8*)(Bs + (wn * (BN / 2) + ni * 16 + lr) * LDA + kk * 32 + g * 8);
            #pragma unroll
            for (int mi = 0; mi < FM; mi++)
                #pragma unroll
                for (int ni = 0; ni < FN; ni++)
                    acc[mi][ni] = __builtin_amdgcn_mfma_f32_16x16x32_bf16(af[mi], bfr[ni], acc[mi][ni], 0, 0, 0);
        }
    }

    #pragma unroll
    for (int ni = 0; ni < FN; ni++) {
        int col = n0 + wn * (BN / 2) + ni * 16 + lr;
        float bi = bias[col];
        #pragma unroll
        for (int mi = 0; mi < FM; mi++) {
            #pragma unroll
            for (int jj = 0; jj < 4; jj++) {
                int row = m0 + wm * (BM / 2) + mi * 16 + g * 4 + jj;
                float v = acc[mi][ni][jj] + bi;
                if (RELU) v = fmaxf(v, 0.0f);
                if (OBF16) Cb[(size_t)row * Nn + col] = f2bf(v);
                else       Cf[(size_t)row * Nn + col] = v;
            }
        }
    }
}

// fused GEMM (M=4096, N=256, K=256) + residual + LayerNorm.
__global__ __launch_bounds__(256) void k_gemm_ln(const u16* __restrict__ A, const u16* __restrict__ Bw,
                                                 const float* __restrict__ bias,
                                                 const float* __restrict__ resid,
                                                 const float* __restrict__ gg, const float* __restrict__ bb,
                                                 float* __restrict__ of, u16* __restrict__ ob) {
    constexpr int LDA = 72, Kk = 256;
    __shared__ __align__(16) u16 As[16 * LDA];
    __shared__ __align__(16) u16 Bs[256 * LDA];
    int tid = threadIdx.x, w = tid >> 6, lane = tid & 63;
    int lr = lane & 15, g = lane >> 4;
    int bid = blockIdx.x;
    bid = (bid & 7) * 32 + (bid >> 3);
    int m0 = bid * 16;
    int trow = tid >> 3, tcol = (tid & 7) << 3;

    f32x4 acc[4] = {};

    for (int kb = 0; kb < Kk; kb += 64) {
        if (kb) __syncthreads();
        if (tid < 128) {
            int row = tid >> 3;
            uint4 v = *(const uint4*)(A + (size_t)(m0 + row) * Kk + kb + tcol);
            *(uint4*)(As + row * LDA + tcol) = v;
        }
        #pragma unroll
        for (int r = 0; r < 8; r++) {
            int row = r * 32 + trow;
            uint4 v = *(const uint4*)(Bw + (size_t)row * Kk + kb + tcol);
            *(uint4*)(Bs + row * LDA + tcol) = v;
        }
        __syncthreads();
        #pragma unroll
        for (int kk = 0; kk < 2; kk++) {
            short8 af = *(const short8*)(As + lr * LDA + kk * 32 + g * 8);
            #pragma unroll
            for (int ni = 0; ni < 4; ni++) {
                short8 bfr = *(const short8*)(Bs + (w * 64 + ni * 16 + lr) * LDA + kk * 32 + g * 8);
                acc[ni] = __builtin_amdgcn_mfma_f32_16x16x32_bf16(af, bfr, acc[ni], 0, 0, 0);
            }
        }
    }

    __syncthreads();
    float* Cs = (float*)Bs;                         // [16][260]
    #pragma unroll
    for (int ni = 0; ni < 4; ni++) {
        int col = w * 64 + ni * 16 + lr;
        float bi = bias[col];
        #pragma unroll
        for (int jj = 0; jj < 4; jj++)
            Cs[(g * 4 + jj) * 260 + col] = acc[ni][jj] + bi;
    }
    __syncthreads();

    int row = tid >> 4, c0 = (tid & 15) * 16;
    float v[16];
    float sum = 0.0f, sq = 0.0f;
    #pragma unroll
    for (int i = 0; i < 4; i++) {
        float4 cv = *(float4*)(Cs + row * 260 + c0 + i * 4);
        float4 rv = *(const float4*)(resid + (size_t)(m0 + row) * D_ + c0 + i * 4);
        v[4*i]   = cv.x + rv.x; v[4*i+1] = cv.y + rv.y;
        v[4*i+2] = cv.z + rv.z; v[4*i+3] = cv.w + rv.w;
    }
    #pragma unroll
    for (int i = 0; i < 16; i++) { sum += v[i]; sq += v[i] * v[i]; }
    #pragma unroll
    for (int m = 1; m < 16; m <<= 1) { sum += __shfl_xor(sum, m, 64); sq += __shfl_xor(sq, m, 64); }
    float mean = sum * (1.0f / 256.0f);
    float var  = sq * (1.0f / 256.0f) - mean * mean;
    float rs = rsqrtf(var + 1e-5f);
    float* op = of + (size_t)(m0 + row) * D_ + c0;
    u16*   bp = ob + (size_t)(m0 + row) * D_ + c0;
    #pragma unroll
    for (int i = 0; i < 4; i++) {
        float4 gv = *(const float4*)(gg + c0 + i * 4);
        float4 bv = *(const float4*)(bb + c0 + i * 4);
        float4 o;
        o.x = (v[4*i]   - mean) * rs * gv.x + bv.x;
        o.y = (v[4*i+1] - mean) * rs * gv.y + bv.y;
        o.z = (v[4*i+2] - mean) * rs * gv.z + bv.z;
        o.w = (v[4*i+3] - mean) * rs * gv.w + bv.w;
        *(float4*)(op + i * 4) = o;
        ushort4 ub; ub.x = f2bf(o.x); ub.y = f2bf(o.y); ub.z = f2bf(o.z); ub.w = f2bf(o.w);
        *(ushort4*)(bp + i * 4) = ub;
    }
}

// merged qca+kvca: grid 768 (XCD-chunked).
__global__ __launch_bounds__(256) void k_gemm2(const u16* __restrict__ A0, const u16* __restrict__ W0,
                                               const float* __restrict__ b0, u16* __restrict__ C0,
                                               const u16* __restrict__ A1, const u16* __restrict__ W1,
                                               const float* __restrict__ b1, u16* __restrict__ C1) {
    constexpr int LDA = 72, Kk = 256;
    __shared__ __align__(16) u16 As[64 * LDA];
    __shared__ __align__(16) u16 Bs[64 * LDA];
    int tid = threadIdx.x, w = tid >> 6, lane = tid & 63;
    int lr = lane & 15, g = lane >> 4;
    int wm = w >> 1, wn = w & 1;
    int bid = blockIdx.x;
    bid = (bid & 7) * 96 + (bid >> 3);
    const u16 *A, *Bw; const float* bias; u16* Cb; int Nn, nbn, seg;
    if (bid < 256) { A = A0; Bw = W0; bias = b0; Cb = C0; Nn = 256; nbn = 4; seg = bid; }
    else           { A = A1; Bw = W1; bias = b1; Cb = C1; Nn = 512; nbn = 8; seg = bid - 256; }
    int m0 = (seg / nbn) * 64, n0 = (seg % nbn) * 64;
    int trow = tid >> 3, tcol = (tid & 7) << 3;

    f32x4 acc[2][2] = {};

    for (int kb = 0; kb < Kk; kb += 64) {
        if (kb) __syncthreads();
        #pragma unroll
        for (int r = 0; r < 2; r++) {
            int row = r * 32 + trow;
            uint4 va = *(const uint4*)(A + (size_t)(m0 + row) * Kk + kb + tcol);
            *(uint4*)(As + row * LDA + tcol) = va;
            uint4 vb = *(const uint4*)(Bw + (size_t)(n0 + row) * Kk + kb + tcol);
            *(uint4*)(Bs + row * LDA + tcol) = vb;
        }
        __syncthreads();
        #pragma unroll
        for (int kk = 0; kk < 2; kk++) {
            short8 af[2], bfr[2];
            #pragma unroll
            for (int mi = 0; mi < 2; mi++)
                af[mi] = *(const short8*)(As + (wm * 32 + mi * 16 + lr) * LDA + kk * 32 + g * 8);
            #pragma unroll
            for (int ni = 0; ni < 2; ni++)
                bfr[ni] = *(const short8*)(Bs + (wn * 32 + ni * 16 + lr) * LDA + kk * 32 + g * 8);
            #pragma unroll
            for (int mi = 0; mi < 2; mi++)
                #pragma unroll
                for (int ni = 0; ni < 2; ni++)
                    acc[mi][ni] = __builtin_amdgcn_mfma_f32_16x16x32_bf16(af[mi], bfr[ni], acc[mi][ni], 0, 0, 0);
        }
    }

    #pragma unroll
    for (int ni = 0; ni < 2; ni++) {
        int col = n0 + wn * 32 + ni * 16 + lr;
        float bi = bias[col];
        #pragma unroll
        for (int mi = 0; mi < 2; mi++)
            #pragma unroll
            for (int jj = 0; jj < 4; jj++) {
                int row = m0 + wm * 32 + mi * 16 + g * 4 + jj;
                Cb[(size_t)row * Nn + col] = f2bf(acc[mi][ni][jj] + bi);
            }
    }
}

// ff2 split-K=4: grid 1024; bf16 partials, bias folded into kz==0.
__global__ __launch_bounds__(256) void k_gemm_sk4(const u16* __restrict__ A, const u16* __restrict__ Bw,
                                                  const float* __restrict__ bias, u16* __restrict__ Cp) {
    constexpr int LDA = 72, Nn = 256, Kk = 2048;
    __shared__ __align__(16) u16 As[64 * LDA];
    __shared__ __align__(16) u16 Bs[64 * LDA];
    int tid = threadIdx.x, w = tid >> 6, lane = tid & 63;
    int lr = lane & 15, g = lane >> 4;
    int wm = w >> 1, wn = w & 1;
    int kz = blockIdx.x >> 8;
    int mn = blockIdx.x & 255;
    mn = (mn & 7) * 32 + (mn >> 3);
    int m0 = (mn >> 2) * 64, n0 = (mn & 3) * 64;
    int kbeg = kz * 512;
    int trow = tid >> 3, tcol = (tid & 7) << 3;

    f32x4 acc[2][2] = {};

    for (int kb = kbeg; kb < kbeg + 512; kb += 64) {
        if (kb != kbeg) __syncthreads();
        #pragma unroll
        for (int r = 0; r < 2; r++) {
            int row = r * 32 + trow;
            uint4 va = *(const uint4*)(A + (size_t)(m0 + row) * Kk + kb + tcol);
            *(uint4*)(As + row * LDA + tcol) = va;
            uint4 vb = *(const uint4*)(Bw + (size_t)(n0 + row) * Kk + kb + tcol);
            *(uint4*)(Bs + row * LDA + tcol) = vb;
        }
        __syncthreads();
        #pragma unroll
        for (int kk = 0; kk < 2; kk++) {
            short8 af[2], bfr[2];
            #pragma unroll
            for (int mi = 0; mi < 2; mi++)
                af[mi] = *(const short8*)(As + (wm * 32 + mi * 16 + lr) * LDA + kk * 32 + g * 8);
            #pragma unroll
            for (int ni = 0; ni < 2; ni++)
                bfr[ni] = *(const short8*)(Bs + (wn * 32 + ni * 16 + lr) * LDA + kk * 32 + g * 8);
            #pragma unroll
            for (int mi = 0; mi < 2; mi++)
                #pragma unroll
                for (int ni = 0; ni < 2; ni++)
                    acc[mi][ni] = __builtin_amdgcn_mfma_f32_16x16x32_bf16(af[mi], bfr[ni], acc[mi][ni], 0, 0, 0);
        }
    }

    u16* Cz = Cp + (size_t)kz * NR * Nn;
    #pragma unroll
    for (int ni = 0; ni < 2; ni++) {
        int col = n0 + wn * 32 + ni * 16 + lr;
        float bi = (kz == 0) ? bias[col] : 0.0f;
        #pragma unroll
        for (int mi = 0; mi < 2; mi++)
            #pragma unroll
            for (int jj = 0; jj < 4; jj++) {
                int row = m0 + wm * 32 + mi * 16 + g * 4 + jj;
                Cz[(size_t)row * Nn + col] = f2bf(acc[mi][ni][jj] + bi);
            }
    }
}

// ---------------- MFMA flash attention (HD=32), exp2 softmax, K/V dbuf, 1 barrier/iter ----------------
// Race proof for single barrier: reads of buf[cur^1] all retire before B1(i) (they occurred in
// iter i-1's compute); stbuf(cur^1) executes after B1(i), so no overlap. B1(i+1)'s waitcnt drain
// publishes stbuf before the next iteration's reads.

__global__ __launch_bounds__(256) void k_attn(const u16* __restrict__ qp, int qs,
                                              const u16* __restrict__ kvp, int ks, int koff, int voff,
                                              const float* __restrict__ addv, u16* __restrict__ out) {
    __shared__ __align__(16) u16 Kl[2][128 * 32];
    __shared__ __align__(16) u16 VTl[2][32 * 136];
    __shared__ __align__(16) u16 Pl[4 * 16 * 136];
    __shared__ float Al[2][128];

    int tid = threadIdx.x, w = tid >> 6, lane = tid & 63;
    int lr = lane & 15, g = lane >> 4;
    int blk = blockIdx.x;
    blk = (blk & 7) * 64 + (blk >> 3);
    int qb = blk & 15, h = (blk >> 4) & 7, b = blk >> 7;
    int q0 = qb * 64 + w * 16;
    const float QS2 = 0.17677669529663687f * 1.4426950408889634f;

    short8 qf = *(const short8*)(qp + (size_t)(b * S_ + q0 + lr) * qs + h * 32 + g * 8);

    f32x4 o0 = {0.f, 0.f, 0.f, 0.f}, o1 = {0.f, 0.f, 0.f, 0.f};
    float m_run = -3.0e38f, l_run = 0.0f;
    float sreg[8][4];
    u16* Pw = Pl + w * 16 * 136;

    int key_t = tid >> 1, dh = (tid & 1) * 16;
    const u16* kbase = kvp + (size_t)(b * S_) * ks;

    uint4 ka0, ka1;
    union { uint4 v[2]; u16 s[16]; } vu;
    float alv = 0.0f;
    auto ldregs = [&](int kb) {
        const u16* srck = kbase + (size_t)(kb * 128 + key_t) * ks + koff + h * 32 + dh;
        ka0 = *(const uint4*)srck;
        ka1 = *(const uint4*)(srck + 8);
        const u16* srcv = kbase + (size_t)(kb * 128 + key_t) * ks + voff + h * 32 + dh;
        vu.v[0] = *(const uint4*)srcv;
        vu.v[1] = *(const uint4*)(srcv + 8);
        if (tid < 128) alv = addv[b * S_ + kb * 128 + tid];
    };
    auto stbuf = [&](int buf) {
        *(uint4*)(&Kl[buf][key_t * 32 + dh])     = ka0;
        *(uint4*)(&Kl[buf][key_t * 32 + dh + 8]) = ka1;
        #pragma unroll
        for (int i = 0; i < 16; i++) VTl[buf][(dh + i) * 136 + key_t] = vu.s[i];
        if (tid < 128) Al[buf][tid] = alv;
    };

    ldregs(0); stbuf(0);
    int cur = 0;
    for (int kb = 0; kb < 8; kb++) {
        __syncthreads();                          // buf[cur] visible; prior readers of cur^1 retired

        #pragma unroll
        for (int t = 0; t < 8; t++) {
            short8 kf = *(const short8*)(&Kl[cur][(t * 16 + lr) * 32 + g * 8]);
            f32x4 z = {0.f, 0.f, 0.f, 0.f};
            f32x4 st = __builtin_amdgcn_mfma_f32_16x16x32_bf16(kf, qf, z, 0, 0, 0);
            #pragma unroll
            for (int jj = 0; jj < 4; jj++) sreg[t][jj] = st[jj] * QS2 + Al[cur][t * 16 + g * 4 + jj];
        }

        if (kb < 7) ldregs(kb + 1);               // issue prefetch; latency hides under softmax

        float mb = -3.0e38f;
        #pragma unroll
        for (int t = 0; t < 8; t++)
            #pragma unroll
            for (int jj = 0; jj < 4; jj++) mb = fmaxf(mb, sreg[t][jj]);
        mb = fmaxf(mb, __shfl_xor(mb, 16, 64));
        mb = fmaxf(mb, __shfl_xor(mb, 32, 64));
        float mnew = fmaxf(m_run, mb);
        float sc = __builtin_amdgcn_exp2f(m_run - mnew);
        float ls = 0.f;
        #pragma unroll
        for (int t = 0; t < 8; t++)
            #pragma unroll
            for (int jj = 0; jj < 4; jj++) {
                float p = __builtin_amdgcn_exp2f(sreg[t][jj] - mnew);
                sreg[t][jj] = p; ls += p;
            }
        ls += __shfl_xor(ls, 16, 64); ls += __shfl_xor(ls, 32, 64);
        l_run = l_run * sc + ls; m_run = mnew;
        #pragma unroll
        for (int jj = 0; jj < 4; jj++) {
            float scj = __shfl(sc, 20 * g + jj, 64);
            o0[jj] *= scj; o1[jj] *= scj;
        }

        #pragma unroll
        for (int t = 0; t < 8; t++) {
            u32 u0 = (u32)f2bf(sreg[t][0]) | ((u32)f2bf(sreg[t][1]) << 16);
            u32 u1 = (u32)f2bf(sreg[t][2]) | ((u32)f2bf(sreg[t][3]) << 16);
            *(uint2*)(Pw + lr * 136 + t * 16 + g * 4) = make_uint2(u0, u1);
        }

        if (kb < 7) stbuf(cur ^ 1);               // vmcnt wait here; PV below covers the tail

        #pragma unroll
        for (int c = 0; c < 4; c++) {
            short8 pa = *(const short8*)(Pw + lr * 136 + c * 32 + g * 8);
            short8 v0 = *(const short8*)(&VTl[cur][lr * 136 + c * 32 + g * 8]);
            short8 v1 = *(const short8*)(&VTl[cur][(16 + lr) * 136 + c * 32 + g * 8]);
            o0 = __builtin_amdgcn_mfma_f32_16x16x32_bf16(pa, v0, o0, 0, 0, 0);
            o1 = __builtin_amdgcn_mfma_f32_16x16x32_bf16(pa, v1, o1, 0, 0, 0);
        }

        cur ^= 1;
    }

    float li = 1.0f / l_run;
    #pragma unroll
    for (int jj = 0; jj < 4; jj++) {
        float lij = __shfl(li, 20 * g + jj, 64);
        int r = q0 + g * 4 + jj;
        u16* op = out + (size_t)(b * S_ + r) * 256 + h * 32;
        op[lr]      = f2bf(o0[jj] * lij);
        op[16 + lr] = f2bf(o1[jj] * lij);
    }
}

// ---------------- host orchestration ----------------

extern "C" void kernel_launch(void* const* d_in, const int* in_sizes, int n_in,
                              void* d_out, int out_size, void* d_ws, size_t ws_size,
                              hipStream_t stream) {
    const int* x                = (const int*)d_in[0];
    const unsigned char* mask   = (const unsigned char*)d_in[1];
    const float* codebook       = (const float*)d_in[2];
    const float* pos            = (const float*)d_in[3];
    const float* enc_qkv_w = (const float*)d_in[4];  const float* enc_qkv_b = (const float*)d_in[5];
    const float* enc_out_w = (const float*)d_in[6];  const float* enc_out_b = (const float*)d_in[7];
    const float* enc_ff1_w = (const float*)d_in[8];  const float* enc_ff1_b = (const float*)d_in[9];
    const float* enc_ff2_w = (const float*)d_in[10]; const float* enc_ff2_b = (const float*)d_in[11];
    const float* enc_ln1_g = (const float*)d_in[12]; const float* enc_ln1_b = (const float*)d_in[13];
    const float* enc_ln2_g = (const float*)d_in[14]; const float* enc_ln2_b = (const float*)d_in[15];
    const float* dec_sa_qkv_w = (const float*)d_in[16]; const float* dec_sa_qkv_b = (const float*)d_in[17];
    const float* dec_sa_out_w = (const float*)d_in[18]; const float* dec_sa_out_b = (const float*)d_in[19];
    const float* dec_ca_qkv_w = (const float*)d_in[20]; const float* dec_ca_qkv_b = (const float*)d_in[21];
    const float* dec_ca_out_w = (const float*)d_in[22]; const float* dec_ca_out_b = (const float*)d_in[23];
    const float* dec_ff1_w = (const float*)d_in[24]; const float* dec_ff1_b = (const float*)d_in[25];
    const float* dec_ff2_w = (const float*)d_in[26]; const float* dec_ff2_b = (const float*)d_in[27];
    const float* dec_ln1_g = (const float*)d_in[28]; const float* dec_ln1_b = (const float*)d_in[29];
    const float* dec_ln2_g = (const float*)d_in[30]; const float* dec_ln2_b = (const float*)d_in[31];
    const float* dec_ln3_g = (const float*)d_in[32]; const float* dec_ln3_b = (const float*)d_in[33];

    char* ws = (char*)d_ws; size_t off = 0;
    auto alloc = [&](size_t b) { char* p = ws + off; off += (b + 255) & ~(size_t)255; return p; };

    u16* w_eqkv  = (u16*)alloc((size_t)786432 * 2);
    u16* w_eout  = (u16*)alloc((size_t)262144 * 2);
    u16* w_eff1  = (u16*)alloc((size_t)2097152 * 2);
    u16* w_eff2  = (u16*)alloc((size_t)2097152 * 2);
    u16* w_dsaq  = (u16*)alloc((size_t)786432 * 2);
    u16* w_dsao  = (u16*)alloc((size_t)262144 * 2);
    u16* w_dcaq  = (u16*)alloc((size_t)786432 * 2);
    u16* w_dcao  = (u16*)alloc((size_t)262144 * 2);
    u16* w_dff1  = (u16*)alloc((size_t)2097152 * 2);
    u16* w_dff2  = (u16*)alloc((size_t)2097152 * 2);
    u16*   wsa   = (u16*)  alloc((size_t)4 * 65536 * 2);
    float* bsa   = (float*)alloc((size_t)4 * 256 * 4);
    float* h_f   = (float*)alloc((size_t)NR * D_ * 4);
    u16*   h_b   = (u16*)  alloc((size_t)NR * D_ * 2);
    float* ctx_f = (float*)alloc((size_t)NR * D_ * 4);
    u16*   ctx_b = (u16*)  alloc((size_t)NR * D_ * 2);
    float* dd_f  = (float*)alloc((size_t)NR * D_ * 4);
    u16*   dd_b  = (u16*)  alloc((size_t)NR * D_ * 2);
    u16*   gem_p = (u16*)  alloc((size_t)4 * NR * 256 * 2);
    u16*   attno = (u16*)  alloc((size_t)NR * 256 * 2);
    float* addv  = (float*)alloc((size_t)NR * 4);
    float* addvz = (float*)alloc((size_t)NR * 4);
    u16* scr = (u16*)alloc((size_t)NR * 2048 * 2);
    u16* qkv_b = scr;
    u16* ffh_b = scr;
    u16* qca_b = scr;
    u16* kvca_b = scr + (size_t)NR * 256;
    (void)in_sizes; (void)n_in;

    if (off > ws_size) {
        k_fillf<<<(out_size + 255) / 256, 256, 0, stream>>>((float*)d_out, out_size, 1000.0f);
        return;
    }

    k_prep<<<4096, 256, 0, stream>>>(enc_qkv_w, enc_out_w, enc_ff1_w, enc_ff2_w,
                                     dec_sa_qkv_w, dec_sa_out_w, dec_ca_qkv_w, dec_ca_out_w,
                                     dec_ff1_w, dec_ff2_w, w_eqkv,
                                     dec_sa_qkv_w, dec_sa_qkv_b, dec_sa_out_w, dec_sa_out_b, wsa, bsa,
                                     x, codebook, pos, mask, h_f, h_b, addv, addvz);

    // ---- encoder ----
    for (int l = 0; l < 4; l++) {
        const u16* inb = l ? ctx_b : h_b;
        const float* inf = l ? ctx_f : h_f;
        k_gemm<64,64,false,true><<<768, 256, 0, stream>>>(inb, w_eqkv + (size_t)l*196608,
            enc_qkv_b + l*768, nullptr, qkv_b, 768, 256);
        k_attn<<<512, 256, 0, stream>>>(qkv_b, 768, qkv_b, 768, 256, 512, addv, attno);
        k_gemm_ln<<<256, 256, 0, stream>>>(attno, w_eout + (size_t)l*65536, enc_out_b + l*256,
            inf, enc_ln1_g + l*256, enc_ln1_b + l*256, ctx_f, ctx_b);
        k_gemm<128,128,true,true><<<512, 256, 0, stream>>>(ctx_b, w_eff1 + (size_t)l*524288,
            enc_ff1_b + l*2048, nullptr, ffh_b, 2048, 256);
        k_gemm_sk4<<<1024, 256, 0, stream>>>(ffh_b, w_eff2 + (size_t)l*524288,
            enc_ff2_b + l*256, gem_p);
        k_ln4<<<1024, 256, 0, stream>>>(ctx_f, gem_p, enc_ln2_g + l*256, enc_ln2_b + l*256, ctx_f, ctx_b);
    }

    // ---- decoder ----
    for (int l = 0; l < 4; l++) {
        const u16* inb = l ? dd_b : h_b;
        const float* inf = l ? dd_f : h_f;
        k_gemm_ln<<<256, 256, 0, stream>>>(inb, wsa + (size_t)l*65536, bsa + l*256,
            inf, dec_ln1_g + l*256, dec_ln1_b + l*256, dd_f, dd_b);
        k_gemm2<<<768, 256, 0, stream>>>(dd_b, w_dcaq + (size_t)l*196608, dec_ca_qkv_b + l*768, qca_b,
                                         ctx_b, w_dcaq + (size_t)l*196608 + 65536,
                                         dec_ca_qkv_b + l*768 + 256, kvca_b);
        k_attn<<<512, 256, 0, stream>>>(qca_b, 256, kvca_b, 512, 0, 256, addvz, attno);
        k_gemm_ln<<<256, 256, 0, stream>>>(attno, w_dcao + (size_t)l*65536, dec_ca_out_b + l*256,
            dd_f, dec_ln2_g + l*256, dec_ln2_b + l*256, dd_f, dd_b);
        k_gemm<128,128,true,true><<<512, 256, 0, stream>>>(dd_b, w_dff1 + (size_t)l*524288,
            dec_ff1_b + l*2048, nullptr, ffh_b, 2048, 256);
        k_gemm_sk4<<<1024, 256, 0, stream>>>(ffh_b, w_dff2 + (size_t)l*524288,
            dec_ff2_b + l*256, gem_p);
        k_ln4<<<1024, 256, 0, stream>>>(dd_f, gem_p, dec_ln3_g + l*256, dec_ln3_b + l*256,
                                        (l == 3) ? (float*)d_out : dd_f, dd_b);
    }
}